// Round 1
// baseline (1896.034 us; speedup 1.0000x reference)
//
#include <hip/hip_runtime.h>
#include <hip/hip_bf16.h>
#include <math.h>

// ---------------- constants ----------------
#define N_NODES 20000
#define N_EDGES 200000
#define N_PAIRS 10000
#define T_SLOT 3
#define NH 64
#define PAIR_PAD 10368   // 162*64
#define DM_TILES 162

__device__ inline float wave_max(float v){
  for (int o = 32; o > 0; o >>= 1) v = fmaxf(v, __shfl_xor(v, o));
  return v;
}
__device__ inline float wave_sum(float v){
  for (int o = 32; o > 0; o >>= 1) v += __shfl_xor(v, o);
  return v;
}

// ---------------- input linears -> h [N,192] (slot-padded) ----------------
__global__ void build_h(const float* __restrict__ f0, const float* __restrict__ w0, const float* __restrict__ b0,
                        const float* __restrict__ f1, const float* __restrict__ w1, const float* __restrict__ b1,
                        const float* __restrict__ f2, const float* __restrict__ w2, const float* __restrict__ b2,
                        float* __restrict__ hbuf){
  int n = blockIdx.x, lane = threadIdx.x;
  int t, idx, C; const float *f, *w, *b;
  if (n < 8000)       { t = 0; idx = n;         C = 256; f = f0; w = w0; b = b0; }
  else if (n < 14000) { t = 1; idx = n - 8000;  C = 128; f = f1; w = w1; b = b1; }
  else                { t = 2; idx = n - 14000; C = 64;  f = f2; w = w2; b = b2; }
  __shared__ float xs[256];
  for (int c = lane; c < C; c += 64) xs[c] = f[(size_t)idx * C + c];
  __syncthreads();
  float acc = b[lane];
  for (int c = 0; c < C; c++) acc += xs[c] * w[c * 64 + lane];
  for (int tt = 0; tt < 3; tt++)
    hbuf[(size_t)n * 192 + tt * 64 + lane] = (tt == t) ? acc : 0.f;
}

// ---------------- per-slot l2 norm of head-mean -> o slice k ----------------
// S: [N, H, 192] rows (n*H+h)*192 ; writes o[n, t*256 + k*64 + lane]
__global__ void emb_kernel(const float* __restrict__ S, float* __restrict__ o, int H, int k){
  int wid = threadIdx.x >> 6, lane = threadIdx.x & 63;
  int n = blockIdx.x * 4 + wid;
  if (n >= N_NODES) return;
  const float* base = S + (size_t)n * H * 192;
  float v[3];
  float invH = 1.f / (float)H;
  for (int t = 0; t < 3; t++){
    float s = 0.f;
    for (int h = 0; h < H; h++) s += base[h * 192 + t * 64 + lane];
    v[t] = s * invH;
  }
  for (int t = 0; t < 3; t++){
    float ss = wave_sum(v[t] * v[t]);
    float scale = 1.f / fmaxf(sqrtf(ss), 1e-12f);
    o[(size_t)n * 768 + t * 256 + k * 64 + lane] = v[t] * scale;
  }
}

// ---------------- CSR build ----------------
__global__ void zero_init(int* __restrict__ csr_cnt, int* __restrict__ cnt5, int* __restrict__ pos5,
                          float* __restrict__ score, int* __restrict__ pairs){
  int i = blockIdx.x * 256 + threadIdx.x;
  if (i < N_NODES) csr_cnt[i] = 0;
  if (i < 8) { cnt5[i] = 0; pos5[i] = 0; }
  if (i < N_PAIRS) score[i] = 0.f;
  if (i < PAIR_PAD) pairs[i] = -1;
}

__global__ void count_k(const int* __restrict__ dst, int* __restrict__ csr_cnt,
                        const int* __restrict__ mid, int* __restrict__ cnt5){
  int e = blockIdx.x * 256 + threadIdx.x;
  if (e < N_EDGES) atomicAdd(&csr_cnt[dst[e]], 1);
  if (e < N_PAIRS) atomicAdd(&cnt5[mid[e]], 1);
}

__global__ void scan_k(const int* __restrict__ cnt, int* __restrict__ coff, int* __restrict__ cpos,
                       const int* __restrict__ cnt5, int* __restrict__ off5){
  __shared__ int sums[256];
  int t = threadIdx.x;
  const int CH = 79; // 256*79 = 20224 >= 20000
  int base = t * CH;
  int s = 0;
  for (int i = 0; i < CH; i++){ int idx = base + i; if (idx < N_NODES) s += cnt[idx]; }
  sums[t] = s;
  __syncthreads();
  for (int o = 1; o < 256; o <<= 1){
    int v = (t >= o) ? sums[t - o] : 0;
    __syncthreads();
    sums[t] += v;
    __syncthreads();
  }
  int run = sums[t] - s; // exclusive prefix of this chunk
  for (int i = 0; i < CH; i++){
    int idx = base + i;
    if (idx < N_NODES){ coff[idx] = run; cpos[idx] = run; run += cnt[idx]; }
  }
  if (t == 255) coff[N_NODES] = N_EDGES;
  if (t == 0){
    int r0 = 0;
    for (int r = 0; r < 5; r++){ off5[r] = r0; r0 += ((cnt5[r] + 63) >> 6) << 6; }
  }
}

__global__ void scatter_k(const int* __restrict__ dst, int* __restrict__ cpos, int* __restrict__ eid,
                          const int* __restrict__ mid, const int* __restrict__ off5,
                          int* __restrict__ pos5, int* __restrict__ pairs){
  int e = blockIdx.x * 256 + threadIdx.x;
  if (e < N_EDGES){
    int p = atomicAdd(&cpos[dst[e]], 1);
    eid[p] = e;
  }
  if (e < N_PAIRS){
    int r = mid[e];
    int p = off5[r] + atomicAdd(&pos5[r], 1);
    pairs[p] = e;
  }
}

// ---------------- tiny per-relation edge-attention table ee5[r,h] ----------------
__global__ void ee5_kernel(const float* __restrict__ eetab, const float* __restrict__ We,
                           const float* __restrict__ ae, float* __restrict__ ee5, int H){
  int r = blockIdx.x;
  int h = threadIdx.x >> 6, lane = threadIdx.x & 63;
  float v = 0.f;
  for (int k = 0; k < 64; k++) v += eetab[r * 64 + k] * We[k * H * 64 + h * 64 + lane];
  v *= ae[h * 64 + lane];
  v = wave_sum(v);
  if (lane == 0) ee5[r * H + h] = v;
}

// ---------------- slot projection: feat[n,h,t*64+j] = sum_c x[n,t,c] W[t,c,h*64+j] ----------------
// LAYER 0: x from hbuf [n*192 + t*64+c] (nonzero only for t==type(n)), C=64,  HO=256
// LAYER 1: x from prev out [ (n*4 + c>>6)*192 + t*64 + (c&63) ],       C=256, HO=256
// LAYER 2: same input as 1,                                             C=256, HO=64
template<int LAYER>
__global__ void proj_kernel(const float* __restrict__ Xin, const float* __restrict__ W,
                            float* __restrict__ feat){
  constexpr int C  = (LAYER == 0) ? 64 : 256;
  constexpr int NO = (LAYER == 2) ? 64 : 256;
  constexpr int H  = NO / 64;
  constexpr int NG = 256 / NO;   // node groups per block
  constexpr int NPT = 16 / NG;   // nodes per thread
  const int n0 = blockIdx.x * 16;
  const int tid = threadIdx.x;
  const int d = tid % NO, ig = tid / NO;
  const int h = d >> 6, jj = d & 63;
  __shared__ float x_s[16][C];
  __shared__ float w_s[16][NO];
  for (int t = 0; t < 3; t++){
    for (int idx = tid; idx < 16 * C; idx += 256){
      int i = idx / C, c = idx % C;
      int n = n0 + i;
      float x;
      if (LAYER == 0){
        int tt = (n < 8000) ? 0 : ((n < 14000) ? 1 : 2);
        x = (tt == t) ? Xin[(size_t)n * 192 + t * 64 + c] : 0.f;
      } else {
        x = Xin[((size_t)n * 4 + (c >> 6)) * 192 + t * 64 + (c & 63)];
      }
      x_s[i][c] = x;
    }
    __syncthreads();
    float acc[NPT];
#pragma unroll
    for (int j = 0; j < NPT; j++) acc[j] = 0.f;
    for (int kk = 0; kk < C; kk += 16){
      for (int idx = tid; idx < 16 * NO; idx += 256){
        int k = idx / NO, dj = idx % NO;
        w_s[k][dj] = W[((size_t)t * C + kk + k) * NO + dj];
      }
      __syncthreads();
#pragma unroll
      for (int k = 0; k < 16; k++){
        float wv = w_s[k][d];
#pragma unroll
        for (int j = 0; j < NPT; j++)
          acc[j] += x_s[ig + j * NG][kk + k] * wv;
      }
      __syncthreads();
    }
    for (int j = 0; j < NPT; j++){
      int n = n0 + ig + j * NG;
      feat[((size_t)n * H + h) * 192 + t * 64 + jj] = acc[j];
    }
    __syncthreads();
  }
}

// ---------------- el/er: dot(feat[n,h,:], al[h,:]/ar[h,:]) ----------------
__global__ void elr_kernel(const float* __restrict__ feat, const float* __restrict__ al,
                           const float* __restrict__ ar, float* __restrict__ el,
                           float* __restrict__ er, int H, int total){
  int wid = threadIdx.x >> 6, lane = threadIdx.x & 63;
  int gw = blockIdx.x * 4 + wid;   // = n*H + h
  if (gw >= total) return;
  int h = gw % H;
  const float* f = feat + (size_t)gw * 192;
  float sl = 0.f, sr = 0.f;
  for (int i = 0; i < 3; i++){
    int dd = i * 64 + lane;
    float v = f[dd];
    sl += v * al[h * 192 + dd];
    sr += v * ar[h * 192 + dd];
  }
  sl = wave_sum(sl); sr = wave_sum(sr);
  if (lane == 0){ el[gw] = sl; er[gw] = sr; }
}

// ---------------- per-dst edge softmax (wave per node) ----------------
// mode 0: a = softmax                     -> aout[e*4+h]
// mode 1: a = 0.95*softmax + 0.05*aprev   -> aout[e*4+h]
// mode 2 (H=1): w2[e] = 0.95*softmax + 0.05*mean_h(aprev[e,0..3]) -> aout[e]
__global__ void edge_softmax_k(const int* __restrict__ csr_off, const int* __restrict__ eid,
                               const int* __restrict__ srcv, const int* __restrict__ et,
                               const float* __restrict__ el, const float* __restrict__ er,
                               const float* __restrict__ ee5,
                               const float* __restrict__ aprev, float* __restrict__ aout,
                               int H, int mode){
  int wid = threadIdx.x >> 6, lane = threadIdx.x & 63;
  int n = blockIdx.x * 4 + wid;
  if (n >= N_NODES) return;
  int off = csr_off[n], cnt = csr_off[n + 1] - off;
  if (cnt == 0) return;
  int stride = (mode == 2) ? 1 : 4;
  for (int h = 0; h < H; h++){
    float erv = er[n * H + h];
    float m = -1e30f;
    for (int b = lane; b < cnt; b += 64){
      int e = eid[off + b];
      float lg = el[srcv[e] * H + h] + erv + ee5[et[e] * H + h];
      lg = (lg >= 0.f) ? lg : 0.2f * lg;
      aout[(size_t)e * stride + h] = lg;
      m = fmaxf(m, lg);
    }
    m = wave_max(m);
    float s = 0.f;
    for (int b = lane; b < cnt; b += 64){
      int e = eid[off + b];
      float ev = expf(aout[(size_t)e * stride + h] - m);
      aout[(size_t)e * stride + h] = ev;
      s += ev;
    }
    s = wave_sum(s);
    float inv = 1.f / s;
    for (int b = lane; b < cnt; b += 64){
      int e = eid[off + b];
      float a = aout[(size_t)e * stride + h] * inv;
      if (mode == 1) a = 0.95f * a + 0.05f * aprev[(size_t)e * 4 + h];
      else if (mode == 2){
        float mp = 0.25f * (aprev[(size_t)e * 4] + aprev[(size_t)e * 4 + 1] +
                            aprev[(size_t)e * 4 + 2] + aprev[(size_t)e * 4 + 3]);
        a = 0.95f * a + 0.05f * mp;
      }
      aout[(size_t)e * stride + h] = a;
    }
  }
}

// ---------------- aggregation: out[n,h,:] = sum_e a[e,h]*feat[src,h,:], optional ELU ----------------
__global__ void agg_kernel(const int* __restrict__ csr_off, const int* __restrict__ eid,
                           const int* __restrict__ srcv, const float* __restrict__ aW,
                           const float* __restrict__ feat, float* __restrict__ outb,
                           int H, int astride, int act){
  int n = blockIdx.x;
  int off = csr_off[n], end = csr_off[n + 1];
  int tot = H * 192;
  for (int idx = threadIdx.x; idx < tot; idx += 256){
    int h = idx / 192, dd = idx % 192;
    float acc = 0.f;
    for (int b = off; b < end; b++){
      int e = eid[b];
      float a = aW[(size_t)e * astride + h];
      int s = srcv[e];
      acc += a * feat[((size_t)s * H + h) * 192 + dd];
    }
    if (act) acc = (acc > 0.f) ? acc : expm1f(acc);
    outb[((size_t)n * H + h) * 192 + dd] = acc;
  }
}

// ---------------- DistMult: relation-pure 64-pair x 64-col tiles, fused (le@M)*re ----------------
__global__ void distmult_gemm(const float* __restrict__ o, const float* __restrict__ dmW,
                              const int* __restrict__ pairs, const int* __restrict__ left,
                              const int* __restrict__ right, const int* __restrict__ mid,
                              float* __restrict__ score){
  const int pt = blockIdx.x, ct = blockIdx.y;
  const int tid = threadIdx.x;
  __shared__ float le_s[64][17];
  __shared__ float M_s[16][65];
  __shared__ int pid_s[64];
  __shared__ int lbase_s[64];
  __shared__ float psum[64];
  __shared__ int r_s;
  if (tid == 0) r_s = -1;
  if (tid < 64){
    int p = pairs[pt * 64 + tid];
    pid_s[tid] = p;
    lbase_s[tid] = (p >= 0) ? left[p] * 768 : -1;
    psum[tid] = 0.f;
  }
  __syncthreads();
  if (tid < 64 && pid_s[tid] >= 0) r_s = mid[pid_s[tid]]; // all valid pairs in tile share r
  __syncthreads();
  int r = r_s;
  if (r < 0) return;
  const float* M = dmW + (size_t)r * 768 * 768 + ct * 64;
  const int tx = tid & 15, ty = tid >> 4;
  float acc[4][4] = {};
  for (int kk = 0; kk < 768; kk += 16){
#pragma unroll
    for (int i = 0; i < 4; i++){
      int idx = i * 256 + tid; int row = idx >> 4, k = idx & 15;
      int b = lbase_s[row];
      le_s[row][k] = (b >= 0) ? o[b + kk + k] : 0.f;
    }
#pragma unroll
    for (int i = 0; i < 4; i++){
      int idx = i * 256 + tid; int k = idx >> 6, j = idx & 63;
      M_s[k][j] = M[(size_t)(kk + k) * 768 + j];
    }
    __syncthreads();
#pragma unroll
    for (int k = 0; k < 16; k++){
      float lev0 = le_s[ty][k], lev1 = le_s[ty + 16][k];
      float lev2 = le_s[ty + 32][k], lev3 = le_s[ty + 48][k];
#pragma unroll
      for (int c = 0; c < 4; c++){
        float m = M_s[k][tx * 4 + c];
        acc[0][c] += lev0 * m; acc[1][c] += lev1 * m;
        acc[2][c] += lev2 * m; acc[3][c] += lev3 * m;
      }
    }
    __syncthreads();
  }
  for (int i = 0; i < 4; i++){
    int row = ty + i * 16;
    int p = pid_s[row];
    if (p >= 0){
      const float* re = o + (size_t)right[p] * 768 + ct * 64 + tx * 4;
      float part = acc[i][0] * re[0] + acc[i][1] * re[1] + acc[i][2] * re[2] + acc[i][3] * re[3];
      atomicAdd(&psum[row], part);
    }
  }
  __syncthreads();
  if (tid < 64){
    int p = pid_s[tid];
    if (p >= 0) atomicAdd(&score[p], psum[tid]);
  }
}

__global__ void sigmoid_k(const float* __restrict__ score, float* __restrict__ out){
  int i = blockIdx.x * 256 + threadIdx.x;
  if (i < N_PAIRS) out[i] = 1.f / (1.f + expf(-score[i]));
}

// ---------------- launcher ----------------
extern "C" void kernel_launch(void* const* d_in, const int* in_sizes, int n_in,
                              void* d_out, int out_size, void* d_ws, size_t ws_size,
                              hipStream_t stream){
  const float* f0 = (const float*)d_in[0];
  const float* w0 = (const float*)d_in[1];
  const float* b0 = (const float*)d_in[2];
  const float* f1 = (const float*)d_in[3];
  const float* w1 = (const float*)d_in[4];
  const float* b1 = (const float*)d_in[5];
  const float* f2 = (const float*)d_in[6];
  const float* w2_ = (const float*)d_in[7];
  const float* b2 = (const float*)d_in[8];
  const float* lW[3]  = {(const float*)d_in[9],  (const float*)d_in[15], (const float*)d_in[21]};
  const float* lal[3] = {(const float*)d_in[10], (const float*)d_in[16], (const float*)d_in[22]};
  const float* lar[3] = {(const float*)d_in[11], (const float*)d_in[17], (const float*)d_in[23]};
  const float* lee[3] = {(const float*)d_in[12], (const float*)d_in[18], (const float*)d_in[24]};
  const float* lwe[3] = {(const float*)d_in[13], (const float*)d_in[19], (const float*)d_in[25]};
  const float* lae[3] = {(const float*)d_in[14], (const float*)d_in[20], (const float*)d_in[26]};
  const float* dmW = (const float*)d_in[27];
  const int* efeat = (const int*)d_in[28];
  const int* srcv  = (const int*)d_in[29];
  const int* dstv  = (const int*)d_in[30];
  const int* left  = (const int*)d_in[31];
  const int* right = (const int*)d_in[32];
  const int* midv  = (const int*)d_in[33];
  float* out = (float*)d_out;

  // workspace layout (fp32 throughout): ~194 MB
  float* o_f  = (float*)d_ws;            // N*768
  float* A_f  = o_f + 15360000;          // feat  [N,4,192]
  float* B_f  = A_f + 15360000;          // h/out [N,4,192]
  float* aA   = B_f + 15360000;          // E*4
  float* aB   = aA + 800000;             // E*4
  float* w2b  = aB + 800000;             // E
  float* elf  = w2b + 200000;            // N*4
  float* erf  = elf + 80000;             // N*4
  float* ee5f = erf + 80000;             // 32
  float* score = ee5f + 32;              // 10016
  int* csr_cnt = (int*)(score + 10016);  // N
  int* csr_off = csr_cnt + 20000;        // N+1 (pad 20004)
  int* csr_pos = csr_off + 20004;        // N
  int* eidb    = csr_pos + 20000;        // E
  int* cnt5    = eidb + 200000;          // 8
  int* off5    = cnt5 + 8;               // 8
  int* pos5    = off5 + 8;               // 8
  int* pairs   = pos5 + 8;               // PAIR_PAD

  build_h<<<20000, 64, 0, stream>>>(f0, w0, b0, f1, w1, b1, f2, w2_, b2, B_f);
  emb_kernel<<<5000, 256, 0, stream>>>(B_f, o_f, 1, 0);
  zero_init<<<80, 256, 0, stream>>>(csr_cnt, cnt5, pos5, score, pairs);
  count_k<<<782, 256, 0, stream>>>(dstv, csr_cnt, midv, cnt5);
  scan_k<<<1, 256, 0, stream>>>(csr_cnt, csr_off, csr_pos, cnt5, off5);
  scatter_k<<<782, 256, 0, stream>>>(dstv, csr_pos, eidb, midv, off5, pos5, pairs);

  // layer 0 (H=4, no residual)
  ee5_kernel<<<5, 256, 0, stream>>>(lee[0], lwe[0], lae[0], ee5f, 4);
  proj_kernel<0><<<1250, 256, 0, stream>>>(B_f, lW[0], A_f);
  elr_kernel<<<20000, 256, 0, stream>>>(A_f, lal[0], lar[0], elf, erf, 4, 80000);
  edge_softmax_k<<<5000, 256, 0, stream>>>(csr_off, eidb, srcv, efeat, elf, erf, ee5f, nullptr, aA, 4, 0);
  agg_kernel<<<20000, 256, 0, stream>>>(csr_off, eidb, srcv, aA, A_f, B_f, 4, 4, 1);
  emb_kernel<<<5000, 256, 0, stream>>>(B_f, o_f, 4, 1);

  // layer 1 (H=4, residual from aA)
  ee5_kernel<<<5, 256, 0, stream>>>(lee[1], lwe[1], lae[1], ee5f, 4);
  proj_kernel<1><<<1250, 256, 0, stream>>>(B_f, lW[1], A_f);
  elr_kernel<<<20000, 256, 0, stream>>>(A_f, lal[1], lar[1], elf, erf, 4, 80000);
  edge_softmax_k<<<5000, 256, 0, stream>>>(csr_off, eidb, srcv, efeat, elf, erf, ee5f, aA, aB, 4, 1);
  agg_kernel<<<20000, 256, 0, stream>>>(csr_off, eidb, srcv, aB, A_f, B_f, 4, 4, 1);
  emb_kernel<<<5000, 256, 0, stream>>>(B_f, o_f, 4, 2);

  // layer 2 (H=1; a2 blends against 4-head a1 -> scalar edge weight w2; no activation)
  ee5_kernel<<<5, 64, 0, stream>>>(lee[2], lwe[2], lae[2], ee5f, 1);
  proj_kernel<2><<<1250, 256, 0, stream>>>(B_f, lW[2], A_f);
  elr_kernel<<<5000, 256, 0, stream>>>(A_f, lal[2], lar[2], elf, erf, 1, 20000);
  edge_softmax_k<<<5000, 256, 0, stream>>>(csr_off, eidb, srcv, efeat, elf, erf, ee5f, aB, w2b, 1, 2);
  agg_kernel<<<20000, 256, 0, stream>>>(csr_off, eidb, srcv, w2b, A_f, B_f, 1, 1, 0);
  emb_kernel<<<5000, 256, 0, stream>>>(B_f, o_f, 1, 3);

  // DistMult + sigmoid
  dim3 dg(DM_TILES, 12);
  distmult_gemm<<<dg, 256, 0, stream>>>(o_f, dmW, pairs, left, right, midv, score);
  sigmoid_k<<<40, 256, 0, stream>>>(score, out);
}

// Round 3
// 1092.792 us; speedup vs baseline: 1.7350x; 1.7350x over previous
//
#include <hip/hip_runtime.h>
#include <math.h>

// ---------------- constants ----------------
#define N_NODES 20000
#define NPAD    20096          // 157*128
#define N_EDGES 200000
#define N_PAIRS 10000
#define PAIR_PAD 10368         // 162*64
#define DM_TILES 162

typedef __attribute__((ext_vector_type(8))) short s16x8;
typedef __attribute__((ext_vector_type(4))) float f32x4;

__device__ inline float wave_max(float v){
  for (int o = 32; o > 0; o >>= 1) v = fmaxf(v, __shfl_xor(v, o));
  return v;
}
__device__ inline float wave_sum(float v){
  for (int o = 32; o > 0; o >>= 1) v += __shfl_xor(v, o);
  return v;
}
__device__ inline short f2bf(float x){
  union { float f; unsigned u; } v; v.f = x;
  unsigned r = (v.u + 0x7FFFu + ((v.u >> 16) & 1u)) >> 16;
  return (short)r;
}
__device__ inline float bf2f(short s){
  union { unsigned u; float f; } v; v.u = ((unsigned)(unsigned short)s) << 16;
  return v.f;
}

// ---------------- input linears -> hbuf fp32 [N,192] + Xb0 bf16 [3][NPAD][64] ----------------
__global__ void build_h(const float* __restrict__ f0, const float* __restrict__ w0, const float* __restrict__ b0,
                        const float* __restrict__ f1, const float* __restrict__ w1, const float* __restrict__ b1,
                        const float* __restrict__ f2, const float* __restrict__ w2, const float* __restrict__ b2,
                        float* __restrict__ hbuf, short* __restrict__ Xb0){
  int n = blockIdx.x, lane = threadIdx.x;
  int t, idx, C; const float *f, *w, *b;
  if (n < 8000)       { t = 0; idx = n;         C = 256; f = f0; w = w0; b = b0; }
  else if (n < 14000) { t = 1; idx = n - 8000;  C = 128; f = f1; w = w1; b = b1; }
  else                { t = 2; idx = n - 14000; C = 64;  f = f2; w = w2; b = b2; }
  __shared__ float xs[256];
  for (int c = lane; c < C; c += 64) xs[c] = f[(size_t)idx * C + c];
  __syncthreads();
  float acc = b[lane];
  for (int c = 0; c < C; c++) acc += xs[c] * w[c * 64 + lane];
  for (int tt = 0; tt < 3; tt++){
    float v = (tt == t) ? acc : 0.f;
    hbuf[(size_t)n * 192 + tt * 64 + lane] = v;
    Xb0[((size_t)(tt * NPAD) + n) * 64 + lane] = f2bf(v);
  }
}

// ---------------- per-slot l2 of fp32 [N,192] -> o_b slice k ----------------
__global__ void emb_f32(const float* __restrict__ S, short* __restrict__ o_b, int k){
  int wid = threadIdx.x >> 6, lane = threadIdx.x & 63;
  int n = blockIdx.x * 4 + wid;
  if (n >= N_NODES) return;
  for (int t = 0; t < 3; t++){
    float v = S[(size_t)n * 192 + t * 64 + lane];
    float ss = wave_sum(v * v);
    float scale = 1.f / fmaxf(sqrtf(ss), 1e-12f);
    o_b[(size_t)n * 768 + t * 256 + k * 64 + lane] = f2bf(v * scale);
  }
}

// ---------------- per-slot l2 of head-mean of Xb12 bf16 -> o_b slice k (H=4) ----------------
__global__ void emb_bf16(const short* __restrict__ Xb, short* __restrict__ o_b, int k){
  int wid = threadIdx.x >> 6, lane = threadIdx.x & 63;
  int n = blockIdx.x * 4 + wid;
  if (n >= N_NODES) return;
  for (int t = 0; t < 3; t++){
    const short* base = Xb + ((size_t)(t * NPAD) + n) * 256 + lane;
    float s = bf2f(base[0]) + bf2f(base[64]) + bf2f(base[128]) + bf2f(base[192]);
    float v = s * 0.25f;
    float ss = wave_sum(v * v);
    float scale = 1.f / fmaxf(sqrtf(ss), 1e-12f);
    o_b[(size_t)n * 768 + t * 256 + k * 64 + lane] = f2bf(v * scale);
  }
}

// ---------------- init ----------------
__global__ void zero_init(int* __restrict__ csr_cnt, int* __restrict__ cnt5, int* __restrict__ pos5,
                          float* __restrict__ score, int* __restrict__ pairs,
                          short* __restrict__ Xb0, short* __restrict__ Xb12){
  int i = blockIdx.x * 256 + threadIdx.x;   // 80*256 = 20480
  if (i < N_NODES) csr_cnt[i] = 0;
  if (i < 8) { cnt5[i] = 0; pos5[i] = 0; }
  if (i < N_PAIRS) score[i] = 0.f;
  if (i < PAIR_PAD) pairs[i] = -1;
  s16x8 z = {};
  if (i < 4608){  // Xb12 pad rows: 3 * 96 * 256 shorts
    int t = (i * 16) / 24576, off = (i * 16) % 24576;
    short* p = Xb12 + ((size_t)(t * NPAD + N_NODES)) * 256 + off;
    *(s16x8*)p = z; *(s16x8*)(p + 8) = z;
  }
  if (i < 1152){  // Xb0 pad rows: 3 * 96 * 64 shorts
    int t = (i * 16) / 6144, off = (i * 16) % 6144;
    short* p = Xb0 + ((size_t)(t * NPAD + N_NODES)) * 64 + off;
    *(s16x8*)p = z; *(s16x8*)(p + 8) = z;
  }
}

__global__ void count_k(const int* __restrict__ dst, int* __restrict__ csr_cnt,
                        const int* __restrict__ mid, int* __restrict__ cnt5){
  int e = blockIdx.x * 256 + threadIdx.x;
  if (e < N_EDGES) atomicAdd(&csr_cnt[dst[e]], 1);
  if (e < N_PAIRS) atomicAdd(&cnt5[mid[e]], 1);
}

__global__ void scan_k(const int* __restrict__ cnt, int* __restrict__ coff, int* __restrict__ cpos,
                       const int* __restrict__ cnt5, int* __restrict__ off5){
  __shared__ int sums[256];
  int t = threadIdx.x;
  const int CH = 79;
  int base = t * CH;
  int s = 0;
  for (int i = 0; i < CH; i++){ int idx = base + i; if (idx < N_NODES) s += cnt[idx]; }
  sums[t] = s;
  __syncthreads();
  for (int o = 1; o < 256; o <<= 1){
    int v = (t >= o) ? sums[t - o] : 0;
    __syncthreads();
    sums[t] += v;
    __syncthreads();
  }
  int run = sums[t] - s;
  for (int i = 0; i < CH; i++){
    int idx = base + i;
    if (idx < N_NODES){ coff[idx] = run; cpos[idx] = run; run += cnt[idx]; }
  }
  if (t == 255) coff[N_NODES] = N_EDGES;
  if (t == 0){
    int r0 = 0;
    for (int r = 0; r < 5; r++){ off5[r] = r0; r0 += ((cnt5[r] + 63) >> 6) << 6; }
  }
}

__global__ void scatter_k(const int* __restrict__ dst, int* __restrict__ cpos, int* __restrict__ eid,
                          const int* __restrict__ mid, const int* __restrict__ off5,
                          int* __restrict__ pos5, int* __restrict__ pairs){
  int e = blockIdx.x * 256 + threadIdx.x;
  if (e < N_EDGES){
    int p = atomicAdd(&cpos[dst[e]], 1);
    eid[p] = e;
  }
  if (e < N_PAIRS){
    int r = mid[e];
    int p = off5[r] + atomicAdd(&pos5[r], 1);
    pairs[p] = e;
  }
}

// ---------------- ee5[r,h] ----------------
__global__ void ee5_kernel(const float* __restrict__ eetab, const float* __restrict__ We,
                           const float* __restrict__ ae, float* __restrict__ ee5, int H){
  int r = blockIdx.x;
  int h = threadIdx.x >> 6, lane = threadIdx.x & 63;
  float v = 0.f;
  for (int k = 0; k < 64; k++) v += eetab[r * 64 + k] * We[k * H * 64 + h * 64 + lane];
  v *= ae[h * 64 + lane];
  v = wave_sum(v);
  if (lane == 0) ee5[r * H + h] = v;
}

// ---------------- fp32 [R][Cc] -> bf16 [Cc][R] (batched transpose) ----------------
__global__ void transpose_bf16(const float* __restrict__ src, short* __restrict__ dst, int R, int Cc){
  __shared__ float tile[32][33];
  const float* s = src + (size_t)blockIdx.z * R * Cc;
  short* d = dst + (size_t)blockIdx.z * R * Cc;
  int r0 = blockIdx.x * 32, c0 = blockIdx.y * 32;
  int tx = threadIdx.x & 31, ty = threadIdx.x >> 5;   // 8 rows of 32
  for (int i = 0; i < 32; i += 8){
    int r = r0 + ty + i;
    tile[ty + i][tx] = (r < R && c0 + tx < Cc) ? s[(size_t)r * Cc + c0 + tx] : 0.f;
  }
  __syncthreads();
  for (int i = 0; i < 32; i += 8){
    int c = c0 + ty + i;
    if (c < Cc && r0 + tx < R)
      d[(size_t)c * R + r0 + tx] = f2bf(tile[tx][ty + i]);
  }
}

// ---------------- MFMA slot projection ----------------
// Xb bf16 [3][NPAD][C], Wt bf16 [3][NO][C]; feat fp32 [(n*H+h)*192 + t*64 + jj]
// grid (NPAD/128, NO/64, 3); 256 threads = 4 waves; wave = 32 rows x 64 cols
template<int C, int NO>
__global__ void mfma_proj(const short* __restrict__ Xb, const short* __restrict__ Wt,
                          float* __restrict__ feat){
  constexpr int H = NO / 64;
  const int n0 = blockIdx.x * 128;
  const int ct = blockIdx.y;
  const int t  = blockIdx.z;
  const int tid = threadIdx.x;
  const int w = tid >> 6, lane = tid & 63;
  const int quad = lane >> 4, ln = lane & 15;
  __shared__ __attribute__((aligned(16))) short A_s[128 * 32];
  __shared__ __attribute__((aligned(16))) short B_s[64 * 32];
  const short* Xt  = Xb + (size_t)t * NPAD * C;
  const short* Wtt = Wt + ((size_t)t * NO + ct * 64) * C;
  f32x4 acc[2][4] = {};
  for (int kk = 0; kk < C; kk += 32){
    {
      int row = tid >> 1, half = tid & 1;
      const s16x8* g = (const s16x8*)(Xt + (size_t)(n0 + row) * C + kk + half * 16);
      s16x8 v0 = g[0], v1 = g[1];
      *(s16x8*)(A_s + row * 32 + half * 16) = v0;
      *(s16x8*)(A_s + row * 32 + half * 16 + 8) = v1;
    }
    {
      int row = tid >> 2, chunk = tid & 3;
      s16x8 v = *(const s16x8*)(Wtt + (size_t)row * C + kk + chunk * 8);
      *(s16x8*)(B_s + row * 32 + chunk * 8) = v;
    }
    __syncthreads();
    s16x8 af0 = *(s16x8*)(A_s + (w * 32 + ln) * 32 + quad * 8);
    s16x8 af1 = *(s16x8*)(A_s + (w * 32 + 16 + ln) * 32 + quad * 8);
    s16x8 bf[4];
#pragma unroll
    for (int b = 0; b < 4; b++) bf[b] = *(s16x8*)(B_s + (b * 16 + ln) * 32 + quad * 8);
#pragma unroll
    for (int b = 0; b < 4; b++){
      acc[0][b] = __builtin_amdgcn_mfma_f32_16x16x32_bf16(af0, bf[b], acc[0][b], 0, 0, 0);
      acc[1][b] = __builtin_amdgcn_mfma_f32_16x16x32_bf16(af1, bf[b], acc[1][b], 0, 0, 0);
    }
    __syncthreads();
  }
#pragma unroll
  for (int ar = 0; ar < 2; ar++){
#pragma unroll
    for (int i = 0; i < 4; i++){
      int n = n0 + w * 32 + ar * 16 + quad * 4 + i;
      if (n >= N_NODES) continue;
#pragma unroll
      for (int b = 0; b < 4; b++){
        int d = ct * 64 + b * 16 + ln;
        int h = d >> 6, jj = d & 63;
        feat[((size_t)n * H + h) * 192 + t * 64 + jj] = acc[ar][b][i];
      }
    }
  }
}

// ---------------- el/er ----------------
__global__ void elr_kernel(const float* __restrict__ feat, const float* __restrict__ al,
                           const float* __restrict__ ar, float* __restrict__ el,
                           float* __restrict__ er, int H, int total){
  int wid = threadIdx.x >> 6, lane = threadIdx.x & 63;
  int gw = blockIdx.x * 4 + wid;
  if (gw >= total) return;
  int h = gw % H;
  const float* f = feat + (size_t)gw * 192;
  float sl = 0.f, sr = 0.f;
  for (int i = 0; i < 3; i++){
    int dd = i * 64 + lane;
    float v = f[dd];
    sl += v * al[h * 192 + dd];
    sr += v * ar[h * 192 + dd];
  }
  sl = wave_sum(sl); sr = wave_sum(sr);
  if (lane == 0){ el[gw] = sl; er[gw] = sr; }
}

// ---------------- per-dst edge softmax ----------------
__global__ void edge_softmax_k(const int* __restrict__ csr_off, const int* __restrict__ eid,
                               const int* __restrict__ srcv, const int* __restrict__ et,
                               const float* __restrict__ el, const float* __restrict__ er,
                               const float* __restrict__ ee5,
                               const float* __restrict__ aprev, float* __restrict__ aout,
                               int H, int mode){
  int wid = threadIdx.x >> 6, lane = threadIdx.x & 63;
  int n = blockIdx.x * 4 + wid;
  if (n >= N_NODES) return;
  int off = csr_off[n], cnt = csr_off[n + 1] - off;
  if (cnt == 0) return;
  int stride = (mode == 2) ? 1 : 4;
  for (int h = 0; h < H; h++){
    float erv = er[n * H + h];
    float m = -1e30f;
    for (int b = lane; b < cnt; b += 64){
      int e = eid[off + b];
      float lg = el[srcv[e] * H + h] + erv + ee5[et[e] * H + h];
      lg = (lg >= 0.f) ? lg : 0.2f * lg;
      aout[(size_t)e * stride + h] = lg;
      m = fmaxf(m, lg);
    }
    m = wave_max(m);
    float s = 0.f;
    for (int b = lane; b < cnt; b += 64){
      int e = eid[off + b];
      float ev = expf(aout[(size_t)e * stride + h] - m);
      aout[(size_t)e * stride + h] = ev;
      s += ev;
    }
    s = wave_sum(s);
    float inv = 1.f / s;
    for (int b = lane; b < cnt; b += 64){
      int e = eid[off + b];
      float a = aout[(size_t)e * stride + h] * inv;
      if (mode == 1) a = 0.95f * a + 0.05f * aprev[(size_t)e * 4 + h];
      else if (mode == 2){
        float mp = 0.25f * (aprev[(size_t)e * 4] + aprev[(size_t)e * 4 + 1] +
                            aprev[(size_t)e * 4 + 2] + aprev[(size_t)e * 4 + 3]);
        a = 0.95f * a + 0.05f * mp;
      }
      aout[(size_t)e * stride + h] = a;
    }
  }
}

// ---------------- aggregation ----------------
// out[n,h,dd] = sum_e a[e,h]*feat[src,h,dd]; optional ELU; write bf16 X (next layer) and/or fp32
__global__ void agg_kernel(const int* __restrict__ csr_off, const int* __restrict__ eid,
                           const int* __restrict__ srcv, const float* __restrict__ aW,
                           const float* __restrict__ feat,
                           float* __restrict__ outf, short* __restrict__ outb,
                           int H, int astride, int act){
  int n = blockIdx.x;
  int off = csr_off[n], end = csr_off[n + 1];
  int tot = H * 192;
  for (int idx = threadIdx.x; idx < tot; idx += 256){
    int h = idx / 192, dd = idx % 192;
    float acc = 0.f;
    for (int b = off; b < end; b++){
      int e = eid[b];
      float a = aW[(size_t)e * astride + h];
      int s = srcv[e];
      acc += a * feat[((size_t)s * H + h) * 192 + dd];
    }
    if (act) acc = (acc > 0.f) ? acc : expm1f(acc);
    if (outf) outf[(size_t)n * 192 + dd] = acc;
    if (outb){
      int t = dd >> 6, j = dd & 63;
      outb[((size_t)(t * NPAD) + n) * 256 + h * 64 + j] = f2bf(acc);
    }
  }
}

// ---------------- DistMult via MFMA ----------------
// grid (162, 6); 256 thr = 4 waves; tile = 64 pairs x 128 cols; K=768
__global__ void distmult_mfma(const short* __restrict__ o_b, const short* __restrict__ Mt,
                              const int* __restrict__ pairs, const int* __restrict__ left,
                              const int* __restrict__ right, const int* __restrict__ mid,
                              float* __restrict__ score){
  const int pt = blockIdx.x, ct = blockIdx.y;
  const int tid = threadIdx.x;
  const int w = tid >> 6, lane = tid & 63;
  const int quad = lane >> 4, ln = lane & 15;
  __shared__ __attribute__((aligned(16))) short smem[8192]; // A(2048)+B(4096) in K; RE 64x128 in epilogue
  short* A_s = smem;
  short* B_s = smem + 2048;
  __shared__ int pid_s[64];
  __shared__ int lbase[64];
  if (tid < 64){
    int p = pairs[pt * 64 + tid];
    pid_s[tid] = p;
    lbase[tid] = (p >= 0) ? left[p] * 768 : 0;
  }
  __syncthreads();
  int p0 = pid_s[0];
  if (p0 < 0) return;                  // fully padded tile
  const int r = mid[p0];
  const short* Mr = Mt + (size_t)r * 768 * 768;
  f32x4 acc[8] = {};
  for (int kk = 0; kk < 768; kk += 32){
    {
      int row = tid >> 2, chunk = tid & 3;
      s16x8 v = *(const s16x8*)(o_b + (size_t)lbase[row] + kk + chunk * 8);
      *(s16x8*)(A_s + row * 32 + chunk * 8) = v;
    }
    {
      int row = tid >> 1, half = tid & 1;
      const s16x8* g = (const s16x8*)(Mr + (size_t)(ct * 128 + row) * 768 + kk + half * 16);
      s16x8 v0 = g[0], v1 = g[1];
      *(s16x8*)(B_s + row * 32 + half * 16) = v0;
      *(s16x8*)(B_s + row * 32 + half * 16 + 8) = v1;
    }
    __syncthreads();
    s16x8 af = *(s16x8*)(A_s + (w * 16 + ln) * 32 + quad * 8);
#pragma unroll
    for (int b = 0; b < 8; b++){
      s16x8 bf = *(s16x8*)(B_s + (b * 16 + ln) * 32 + quad * 8);
      acc[b] = __builtin_amdgcn_mfma_f32_16x16x32_bf16(af, bf, acc[b], 0, 0, 0);
    }
    __syncthreads();
  }
  // epilogue: stage RE tile bf16 [64 pairs][128 cols] = 8192 shorts (exactly smem)
  short* RE_s = smem;
  {
    int row = tid >> 2, quarter = tid & 3;   // 4 threads per pair-row, 32 shorts each
    int p = pid_s[row];
    s16x8 v0 = {}, v1 = {}, v2 = {}, v3 = {};
    if (p >= 0){
      const s16x8* g = (const s16x8*)(o_b + (size_t)right[p] * 768 + ct * 128 + quarter * 32);
      v0 = g[0]; v1 = g[1]; v2 = g[2]; v3 = g[3];
    }
    short* dst = RE_s + row * 128 + quarter * 32;
    *(s16x8*)(dst)      = v0;
    *(s16x8*)(dst + 8)  = v1;
    *(s16x8*)(dst + 16) = v2;
    *(s16x8*)(dst + 24) = v3;
  }
  __syncthreads();
#pragma unroll
  for (int i = 0; i < 4; i++){
    int row = w * 16 + quad * 4 + i;
    float s = 0.f;
#pragma unroll
    for (int b = 0; b < 8; b++)
      s += acc[b][i] * bf2f(RE_s[row * 128 + b * 16 + ln]);
    s += __shfl_xor(s, 1); s += __shfl_xor(s, 2);
    s += __shfl_xor(s, 4); s += __shfl_xor(s, 8);
    if (ln == 0){
      int p = pid_s[row];
      if (p >= 0) atomicAdd(&score[p], s);
    }
  }
}

__global__ void sigmoid_k(const float* __restrict__ score, float* __restrict__ out){
  int i = blockIdx.x * 256 + threadIdx.x;
  if (i < N_PAIRS) out[i] = 1.f / (1.f + expf(-score[i]));
}

// ---------------- launcher ----------------
extern "C" void kernel_launch(void* const* d_in, const int* in_sizes, int n_in,
                              void* d_out, int out_size, void* d_ws, size_t ws_size,
                              hipStream_t stream){
  const float* f0 = (const float*)d_in[0];
  const float* w0 = (const float*)d_in[1];
  const float* b0 = (const float*)d_in[2];
  const float* f1 = (const float*)d_in[3];
  const float* w1 = (const float*)d_in[4];
  const float* b1 = (const float*)d_in[5];
  const float* f2 = (const float*)d_in[6];
  const float* w2_ = (const float*)d_in[7];
  const float* b2 = (const float*)d_in[8];
  const float* lW[3]  = {(const float*)d_in[9],  (const float*)d_in[15], (const float*)d_in[21]};
  const float* lal[3] = {(const float*)d_in[10], (const float*)d_in[16], (const float*)d_in[22]};
  const float* lar[3] = {(const float*)d_in[11], (const float*)d_in[17], (const float*)d_in[23]};
  const float* lee[3] = {(const float*)d_in[12], (const float*)d_in[18], (const float*)d_in[24]};
  const float* lwe[3] = {(const float*)d_in[13], (const float*)d_in[19], (const float*)d_in[25]};
  const float* lae[3] = {(const float*)d_in[14], (const float*)d_in[20], (const float*)d_in[26]};
  const float* dmW = (const float*)d_in[27];
  const int* efeat = (const int*)d_in[28];
  const int* srcv  = (const int*)d_in[29];
  const int* dstv  = (const int*)d_in[30];
  const int* left  = (const int*)d_in[31];
  const int* right = (const int*)d_in[32];
  const int* midv  = (const int*)d_in[33];
  float* out = (float*)d_out;

  // ---- workspace layout (~162 MB) ----
  float* A_f   = (float*)d_ws;           // 15,360,000  feat [N,4,192]
  float* hbuf  = A_f + 15360000;         // 3,840,000   h / layer2-out [N,192]
  float* aA    = hbuf + 3840000;         // 800,000
  float* aB    = aA + 800000;            // 800,000
  float* w2b   = aB + 800000;            // 200,000
  float* elf   = w2b + 200000;           // 80,000
  float* erf   = elf + 80000;            // 80,000
  float* ee5f  = erf + 80000;            // 32
  float* score = ee5f + 32;              // 10,016
  int* csr_cnt = (int*)(score + 10016);  // 20,000
  int* csr_off = csr_cnt + 20000;        // 20,004
  int* csr_pos = csr_off + 20004;        // 20,000
  int* eidb    = csr_pos + 20000;        // 200,000
  int* cnt5    = eidb + 200000;          // 8
  int* off5    = cnt5 + 8;               // 8
  int* pos5    = off5 + 8;               // 8
  int* pairs   = pos5 + 8;               // 10,368
  short* o_b   = (short*)(pairs + PAIR_PAD); // 15,360,000  o bf16 [N,768]
  short* Xb0   = o_b + 15360000;         // 3*NPAD*64  = 3,858,432
  short* Xb12  = Xb0 + 3858432;          // 3*NPAD*256 = 15,433,728
  short* Wt0   = Xb12 + 15433728;        // 3*256*64
  short* Wt1   = Wt0 + 49152;            // 3*256*256
  short* Wt2   = Wt1 + 196608;           // 3*64*256
  short* Mt    = Wt2 + 49152;            // 5*768*768

  zero_init<<<80, 256, 0, stream>>>(csr_cnt, cnt5, pos5, score, pairs, Xb0, Xb12);
  build_h<<<N_NODES, 64, 0, stream>>>(f0, w0, b0, f1, w1, b1, f2, w2_, b2, hbuf, Xb0);
  emb_f32<<<5000, 256, 0, stream>>>(hbuf, o_b, 0);
  count_k<<<782, 256, 0, stream>>>(dstv, csr_cnt, midv, cnt5);
  scan_k<<<1, 256, 0, stream>>>(csr_cnt, csr_off, csr_pos, cnt5, off5);
  scatter_k<<<782, 256, 0, stream>>>(dstv, csr_pos, eidb, midv, off5, pos5, pairs);

  // weight prep (bf16 transposes)
  { dim3 g(2, 8, 3);   transpose_bf16<<<g, 256, 0, stream>>>(lW[0], Wt0, 64, 256); }
  { dim3 g(8, 8, 3);   transpose_bf16<<<g, 256, 0, stream>>>(lW[1], Wt1, 256, 256); }
  { dim3 g(8, 2, 3);   transpose_bf16<<<g, 256, 0, stream>>>(lW[2], Wt2, 256, 64); }
  { dim3 g(24, 24, 5); transpose_bf16<<<g, 256, 0, stream>>>(dmW, Mt, 768, 768); }

  // layer 0 (H=4, no residual)
  ee5_kernel<<<5, 256, 0, stream>>>(lee[0], lwe[0], lae[0], ee5f, 4);
  { dim3 g(NPAD / 128, 4, 3); mfma_proj<64, 256><<<g, 256, 0, stream>>>(Xb0, Wt0, A_f); }
  elr_kernel<<<20000, 256, 0, stream>>>(A_f, lal[0], lar[0], elf, erf, 4, 80000);
  edge_softmax_k<<<5000, 256, 0, stream>>>(csr_off, eidb, srcv, efeat, elf, erf, ee5f, nullptr, aA, 4, 0);
  agg_kernel<<<N_NODES, 256, 0, stream>>>(csr_off, eidb, srcv, aA, A_f, nullptr, Xb12, 4, 4, 1);
  emb_bf16<<<5000, 256, 0, stream>>>(Xb12, o_b, 1);

  // layer 1 (H=4, residual aA)
  ee5_kernel<<<5, 256, 0, stream>>>(lee[1], lwe[1], lae[1], ee5f, 4);
  { dim3 g(NPAD / 128, 4, 3); mfma_proj<256, 256><<<g, 256, 0, stream>>>(Xb12, Wt1, A_f); }
  elr_kernel<<<20000, 256, 0, stream>>>(A_f, lal[1], lar[1], elf, erf, 4, 80000);
  edge_softmax_k<<<5000, 256, 0, stream>>>(csr_off, eidb, srcv, efeat, elf, erf, ee5f, aA, aB, 4, 1);
  agg_kernel<<<N_NODES, 256, 0, stream>>>(csr_off, eidb, srcv, aB, A_f, nullptr, Xb12, 4, 4, 1);
  emb_bf16<<<5000, 256, 0, stream>>>(Xb12, o_b, 2);

  // layer 2 (H=1; blends vs 4-head a1 -> scalar edge weight; no activation)
  ee5_kernel<<<5, 64, 0, stream>>>(lee[2], lwe[2], lae[2], ee5f, 1);
  { dim3 g(NPAD / 128, 1, 3); mfma_proj<256, 64><<<g, 256, 0, stream>>>(Xb12, Wt2, A_f); }
  elr_kernel<<<5000, 256, 0, stream>>>(A_f, lal[2], lar[2], elf, erf, 1, 20000);
  edge_softmax_k<<<5000, 256, 0, stream>>>(csr_off, eidb, srcv, efeat, elf, erf, ee5f, aB, w2b, 1, 2);
  agg_kernel<<<N_NODES, 256, 0, stream>>>(csr_off, eidb, srcv, w2b, A_f, hbuf, nullptr, 1, 1, 0);
  emb_f32<<<5000, 256, 0, stream>>>(hbuf, o_b, 3);

  // DistMult + sigmoid
  { dim3 g(DM_TILES, 6); distmult_mfma<<<g, 256, 0, stream>>>(o_b, Mt, pairs, left, right, midv, score); }
  sigmoid_k<<<40, 256, 0, stream>>>(score, out);
}

// Round 4
// 698.421 us; speedup vs baseline: 2.7147x; 1.5647x over previous
//
#include <hip/hip_runtime.h>
#include <math.h>

// ---------------- constants ----------------
#define N_NODES 20000
#define NPAD    20096          // 157*128
#define N_EDGES 200000
#define N_PAIRS 10000
#define PAIR_PAD 10368         // 162*64
#define DM_TILES 162

typedef __attribute__((ext_vector_type(8))) short s16x8;
typedef __attribute__((ext_vector_type(4))) float f32x4;

__device__ inline float wave_max(float v){
  for (int o = 32; o > 0; o >>= 1) v = fmaxf(v, __shfl_xor(v, o));
  return v;
}
__device__ inline float wave_sum(float v){
  for (int o = 32; o > 0; o >>= 1) v += __shfl_xor(v, o);
  return v;
}
__device__ inline short f2bf(float x){
  union { float f; unsigned u; } v; v.f = x;
  unsigned r = (v.u + 0x7FFFu + ((v.u >> 16) & 1u)) >> 16;
  return (short)r;
}
__device__ inline float bf2f(short s){
  union { unsigned u; float f; } v; v.u = ((unsigned)(unsigned short)s) << 16;
  return v.f;
}

// ---------------- input linears -> hbuf fp32 [N,192] + Xb0 bf16 [3][NPAD][64] ----------------
__global__ void build_h(const float* __restrict__ f0, const float* __restrict__ w0, const float* __restrict__ b0,
                        const float* __restrict__ f1, const float* __restrict__ w1, const float* __restrict__ b1,
                        const float* __restrict__ f2, const float* __restrict__ w2, const float* __restrict__ b2,
                        float* __restrict__ hbuf, short* __restrict__ Xb0){
  int n = blockIdx.x, lane = threadIdx.x;
  int t, idx, C; const float *f, *w, *b;
  if (n < 8000)       { t = 0; idx = n;         C = 256; f = f0; w = w0; b = b0; }
  else if (n < 14000) { t = 1; idx = n - 8000;  C = 128; f = f1; w = w1; b = b1; }
  else                { t = 2; idx = n - 14000; C = 64;  f = f2; w = w2; b = b2; }
  __shared__ float xs[256];
  for (int c = lane; c < C; c += 64) xs[c] = f[(size_t)idx * C + c];
  __syncthreads();
  float acc = b[lane];
  for (int c = 0; c < C; c++) acc += xs[c] * w[c * 64 + lane];
  for (int tt = 0; tt < 3; tt++){
    float v = (tt == t) ? acc : 0.f;
    hbuf[(size_t)n * 192 + tt * 64 + lane] = v;
    Xb0[((size_t)(tt * NPAD) + n) * 64 + lane] = f2bf(v);
  }
}

// ---------------- per-slot l2 of fp32 [N,192] -> o_b slice k ----------------
__global__ void emb_f32(const float* __restrict__ S, short* __restrict__ o_b, int k){
  int wid = threadIdx.x >> 6, lane = threadIdx.x & 63;
  int n = blockIdx.x * 4 + wid;
  if (n >= N_NODES) return;
  for (int t = 0; t < 3; t++){
    float v = S[(size_t)n * 192 + t * 64 + lane];
    float ss = wave_sum(v * v);
    float scale = 1.f / fmaxf(sqrtf(ss), 1e-12f);
    o_b[(size_t)n * 768 + t * 256 + k * 64 + lane] = f2bf(v * scale);
  }
}

// ---------------- per-slot l2 of head-mean of Xb12 bf16 -> o_b slice k (H=4) ----------------
__global__ void emb_bf16(const short* __restrict__ Xb, short* __restrict__ o_b, int k){
  int wid = threadIdx.x >> 6, lane = threadIdx.x & 63;
  int n = blockIdx.x * 4 + wid;
  if (n >= N_NODES) return;
  for (int t = 0; t < 3; t++){
    const short* base = Xb + ((size_t)(t * NPAD) + n) * 256 + lane;
    float s = bf2f(base[0]) + bf2f(base[64]) + bf2f(base[128]) + bf2f(base[192]);
    float v = s * 0.25f;
    float ss = wave_sum(v * v);
    float scale = 1.f / fmaxf(sqrtf(ss), 1e-12f);
    o_b[(size_t)n * 768 + t * 256 + k * 64 + lane] = f2bf(v * scale);
  }
}

// ---------------- init ----------------
__global__ void zero_init(int* __restrict__ csr_cnt, int* __restrict__ cnt5, int* __restrict__ pos5,
                          float* __restrict__ score, int* __restrict__ pairs,
                          short* __restrict__ Xb0, short* __restrict__ Xb12){
  int i = blockIdx.x * 256 + threadIdx.x;   // 80*256 = 20480
  if (i < N_NODES) csr_cnt[i] = 0;
  if (i < 8) { cnt5[i] = 0; pos5[i] = 0; }
  if (i < N_PAIRS) score[i] = 0.f;
  if (i < PAIR_PAD) pairs[i] = -1;
  s16x8 z = {};
  if (i < 4608){  // Xb12 pad rows: 3 * 96 * 256 shorts
    int t = (i * 16) / 24576, off = (i * 16) % 24576;
    short* p = Xb12 + ((size_t)(t * NPAD + N_NODES)) * 256 + off;
    *(s16x8*)p = z; *(s16x8*)(p + 8) = z;
  }
  if (i < 1152){  // Xb0 pad rows: 3 * 96 * 64 shorts
    int t = (i * 16) / 6144, off = (i * 16) % 6144;
    short* p = Xb0 + ((size_t)(t * NPAD + N_NODES)) * 64 + off;
    *(s16x8*)p = z; *(s16x8*)(p + 8) = z;
  }
}

__global__ void count_k(const int* __restrict__ dst, int* __restrict__ csr_cnt,
                        const int* __restrict__ mid, int* __restrict__ cnt5){
  int e = blockIdx.x * 256 + threadIdx.x;
  if (e < N_EDGES) atomicAdd(&csr_cnt[dst[e]], 1);
  if (e < N_PAIRS) atomicAdd(&cnt5[mid[e]], 1);
}

__global__ void scan_k(const int* __restrict__ cnt, int* __restrict__ coff, int* __restrict__ cpos,
                       const int* __restrict__ cnt5, int* __restrict__ off5){
  __shared__ int sums[256];
  int t = threadIdx.x;
  const int CH = 79;
  int base = t * CH;
  int s = 0;
  for (int i = 0; i < CH; i++){ int idx = base + i; if (idx < N_NODES) s += cnt[idx]; }
  sums[t] = s;
  __syncthreads();
  for (int o = 1; o < 256; o <<= 1){
    int v = (t >= o) ? sums[t - o] : 0;
    __syncthreads();
    sums[t] += v;
    __syncthreads();
  }
  int run = sums[t] - s;
  for (int i = 0; i < CH; i++){
    int idx = base + i;
    if (idx < N_NODES){ coff[idx] = run; cpos[idx] = run; run += cnt[idx]; }
  }
  if (t == 255) coff[N_NODES] = N_EDGES;
  if (t == 0){
    int r0 = 0;
    for (int r = 0; r < 5; r++){ off5[r] = r0; r0 += ((cnt5[r] + 63) >> 6) << 6; }
  }
}

__global__ void scatter_k(const int* __restrict__ dst, int* __restrict__ cpos, int* __restrict__ eid,
                          const int* __restrict__ mid, const int* __restrict__ off5,
                          int* __restrict__ pos5, int* __restrict__ pairs){
  int e = blockIdx.x * 256 + threadIdx.x;
  if (e < N_EDGES){
    int p = atomicAdd(&cpos[dst[e]], 1);
    eid[p] = e;
  }
  if (e < N_PAIRS){
    int r = mid[e];
    int p = off5[r] + atomicAdd(&pos5[r], 1);
    pairs[p] = e;
  }
}

// ---------------- ee5[r,h] ----------------
__global__ void ee5_kernel(const float* __restrict__ eetab, const float* __restrict__ We,
                           const float* __restrict__ ae, float* __restrict__ ee5, int H){
  int r = blockIdx.x;
  int h = threadIdx.x >> 6, lane = threadIdx.x & 63;
  float v = 0.f;
  for (int k = 0; k < 64; k++) v += eetab[r * 64 + k] * We[k * H * 64 + h * 64 + lane];
  v *= ae[h * 64 + lane];
  v = wave_sum(v);
  if (lane == 0) ee5[r * H + h] = v;
}

// ---------------- fp32 [R][Cc] -> bf16 [Cc][R] (batched transpose) ----------------
__global__ void transpose_bf16(const float* __restrict__ src, short* __restrict__ dst, int R, int Cc){
  __shared__ float tile[32][33];
  const float* s = src + (size_t)blockIdx.z * R * Cc;
  short* d = dst + (size_t)blockIdx.z * R * Cc;
  int r0 = blockIdx.x * 32, c0 = blockIdx.y * 32;
  int tx = threadIdx.x & 31, ty = threadIdx.x >> 5;   // 8 rows of 32
  for (int i = 0; i < 32; i += 8){
    int r = r0 + ty + i;
    tile[ty + i][tx] = (r < R && c0 + tx < Cc) ? s[(size_t)r * Cc + c0 + tx] : 0.f;
  }
  __syncthreads();
  for (int i = 0; i < 32; i += 8){
    int c = c0 + ty + i;
    if (c < Cc && r0 + tx < R)
      d[(size_t)c * R + r0 + tx] = f2bf(tile[tx][ty + i]);
  }
}

// ---------------- MFMA slot projection -> bf16 feat ----------------
// Xb bf16 [3][NPAD][C], Wt bf16 [3][NO][C]; featb bf16 [(n*H+h)*192 + t*64 + jj]
template<int C, int NO>
__global__ void mfma_proj(const short* __restrict__ Xb, const short* __restrict__ Wt,
                          short* __restrict__ featb){
  constexpr int H = NO / 64;
  const int n0 = blockIdx.x * 128;
  const int ct = blockIdx.y;
  const int t  = blockIdx.z;
  const int tid = threadIdx.x;
  const int w = tid >> 6, lane = tid & 63;
  const int quad = lane >> 4, ln = lane & 15;
  __shared__ __attribute__((aligned(16))) short A_s[128 * 32];
  __shared__ __attribute__((aligned(16))) short B_s[64 * 32];
  const short* Xt  = Xb + (size_t)t * NPAD * C;
  const short* Wtt = Wt + ((size_t)t * NO + ct * 64) * C;
  f32x4 acc[2][4] = {};
  for (int kk = 0; kk < C; kk += 32){
    {
      int row = tid >> 1, half = tid & 1;
      const s16x8* g = (const s16x8*)(Xt + (size_t)(n0 + row) * C + kk + half * 16);
      s16x8 v0 = g[0], v1 = g[1];
      *(s16x8*)(A_s + row * 32 + half * 16) = v0;
      *(s16x8*)(A_s + row * 32 + half * 16 + 8) = v1;
    }
    {
      int row = tid >> 2, chunk = tid & 3;
      s16x8 v = *(const s16x8*)(Wtt + (size_t)row * C + kk + chunk * 8);
      *(s16x8*)(B_s + row * 32 + chunk * 8) = v;
    }
    __syncthreads();
    s16x8 af0 = *(s16x8*)(A_s + (w * 32 + ln) * 32 + quad * 8);
    s16x8 af1 = *(s16x8*)(A_s + (w * 32 + 16 + ln) * 32 + quad * 8);
    s16x8 bf[4];
#pragma unroll
    for (int b = 0; b < 4; b++) bf[b] = *(s16x8*)(B_s + (b * 16 + ln) * 32 + quad * 8);
#pragma unroll
    for (int b = 0; b < 4; b++){
      acc[0][b] = __builtin_amdgcn_mfma_f32_16x16x32_bf16(af0, bf[b], acc[0][b], 0, 0, 0);
      acc[1][b] = __builtin_amdgcn_mfma_f32_16x16x32_bf16(af1, bf[b], acc[1][b], 0, 0, 0);
    }
    __syncthreads();
  }
#pragma unroll
  for (int ar = 0; ar < 2; ar++){
#pragma unroll
    for (int i = 0; i < 4; i++){
      int n = n0 + w * 32 + ar * 16 + quad * 4 + i;
      if (n >= N_NODES) continue;
#pragma unroll
      for (int b = 0; b < 4; b++){
        int d = ct * 64 + b * 16 + ln;
        int h = d >> 6, jj = d & 63;
        featb[((size_t)n * H + h) * 192 + t * 64 + jj] = f2bf(acc[ar][b][i]);
      }
    }
  }
}

// ---------------- el/er from bf16 feat ----------------
__global__ void elr_kernel(const short* __restrict__ featb, const float* __restrict__ al,
                           const float* __restrict__ ar, float* __restrict__ el,
                           float* __restrict__ er, int H, int total){
  int wid = threadIdx.x >> 6, lane = threadIdx.x & 63;
  int gw = blockIdx.x * 4 + wid;
  if (gw >= total) return;
  int h = gw % H;
  const short* f = featb + (size_t)gw * 192;
  float sl = 0.f, sr = 0.f;
  for (int i = 0; i < 3; i++){
    int dd = i * 64 + lane;
    float v = bf2f(f[dd]);
    sl += v * al[h * 192 + dd];
    sr += v * ar[h * 192 + dd];
  }
  sl = wave_sum(sl); sr = wave_sum(sr);
  if (lane == 0){ el[gw] = sl; er[gw] = sr; }
}

// ---------------- fused edge-softmax + aggregation (wave per node) ----------------
// MODE 0: a=softmax -> aout[e*4+h]; MODE 1: a=.95sm+.05*aprev[e,h] -> aout
// MODE 2 (H=1): a=.95sm+.05*mean(aprev[e,:]); aout skipped
// ACT: ELU. outb: bf16 [3][NPAD][H*64] (next layer X); outf: fp32 [N,192] (H=1)
template<int H, int MODE, int ACT>
__global__ __launch_bounds__(256) void gat_fused(
    const int* __restrict__ csr_off, const int* __restrict__ eid,
    const int* __restrict__ srcv, const int* __restrict__ et,
    const float* __restrict__ el, const float* __restrict__ er, const float* __restrict__ ee5,
    const float* __restrict__ aprev, float* __restrict__ aout,
    const short* __restrict__ featb, short* __restrict__ outb, float* __restrict__ outf){
  const int wid = threadIdx.x >> 6, lane = threadIdx.x & 63;
  const int n = blockIdx.x * 4 + wid;
  if (n >= N_NODES) return;
  const int off = csr_off[n];
  const int cnt = csr_off[n + 1] - off;
  __shared__ float a_s[4][64][4];
  __shared__ int src_s[4][64];
  constexpr int NC = H * 192 / 8;            // 96 (H=4) or 24 (H=1)
  const int c0 = lane;
  const int h0 = (c0 / 24) % H;
  const int c1 = lane + 64;                  // H=4, lane<32 only
  const int h1 = (c1 / 24) % H;
  float acc0[8] = {}, acc1[8] = {};
  float ern[H];
#pragma unroll
  for (int h = 0; h < H; h++) ern[h] = er[n * H + h];

  if (cnt > 0 && cnt <= 64){
    // ---- phase 1: lane = edge ----
    int e = -1, sidx = 0;
    if (lane < cnt){ e = eid[off + lane]; sidx = srcv[e]; src_s[wid][lane] = sidx; }
    float lg[H];
#pragma unroll
    for (int h = 0; h < H; h++) lg[h] = -1e30f;
    if (lane < cnt){
      int r = et[e];
#pragma unroll
      for (int h = 0; h < H; h++){
        float v = el[sidx * H + h] + ern[h] + ee5[r * H + h];
        lg[h] = (v >= 0.f) ? v : 0.2f * v;
      }
    }
    float ap[4] = {};
    if (MODE > 0 && lane < cnt){
#pragma unroll
      for (int q = 0; q < 4; q++) ap[q] = aprev[(size_t)e * 4 + q];
    }
    float av[H];
#pragma unroll
    for (int h = 0; h < H; h++){
      float mh = wave_max(lg[h]);
      float ex = (lane < cnt) ? __expf(lg[h] - mh) : 0.f;
      float sh = wave_sum(ex);
      float a = ex / sh;
      if (MODE == 1) a = 0.95f * a + 0.05f * ap[h];
      if (MODE == 2) a = 0.95f * a + 0.0125f * (ap[0] + ap[1] + ap[2] + ap[3]);
      av[h] = a;
      if (lane < cnt) a_s[wid][lane][h] = a;
    }
    if (aout && lane < cnt){
#pragma unroll
      for (int h = 0; h < H; h++) aout[(size_t)e * H + h] = av[h];
    }
    // ---- phase 2: lane = chunk ----
    for (int b = 0; b < cnt; b++){
      int s = src_s[wid][b];
      const short* row = featb + (size_t)s * (H * 192);
      if (lane < NC){
        float a = a_s[wid][b][h0];
        s16x8 v = *(const s16x8*)(row + c0 * 8);
#pragma unroll
        for (int i = 0; i < 8; i++) acc0[i] += a * bf2f(v[i]);
      }
      if (H == 4 && lane < 32){
        float a = a_s[wid][b][h1];
        s16x8 v = *(const s16x8*)(row + c1 * 8);
#pragma unroll
        for (int i = 0; i < 8; i++) acc1[i] += a * bf2f(v[i]);
      }
    }
  } else if (cnt > 64){
    // ---- slow path (recompute-based; essentially never taken) ----
    float mh[H], sh[H];
#pragma unroll
    for (int h = 0; h < H; h++){ mh[h] = -1e30f; sh[h] = 0.f; }
    for (int b = lane; b < cnt; b += 64){
      int e = eid[off + b]; int s = srcv[e]; int r = et[e];
#pragma unroll
      for (int h = 0; h < H; h++){
        float v = el[s * H + h] + ern[h] + ee5[r * H + h];
        v = (v >= 0.f) ? v : 0.2f * v;
        mh[h] = fmaxf(mh[h], v);
      }
    }
#pragma unroll
    for (int h = 0; h < H; h++) mh[h] = wave_max(mh[h]);
    for (int b = lane; b < cnt; b += 64){
      int e = eid[off + b]; int s = srcv[e]; int r = et[e];
#pragma unroll
      for (int h = 0; h < H; h++){
        float v = el[s * H + h] + ern[h] + ee5[r * H + h];
        v = (v >= 0.f) ? v : 0.2f * v;
        sh[h] += __expf(v - mh[h]);
      }
    }
#pragma unroll
    for (int h = 0; h < H; h++) sh[h] = wave_sum(sh[h]);
    if (aout){
      for (int b = lane; b < cnt; b += 64){
        int e = eid[off + b]; int s = srcv[e]; int r = et[e];
#pragma unroll
        for (int h = 0; h < H; h++){
          float v = el[s * H + h] + ern[h] + ee5[r * H + h];
          v = (v >= 0.f) ? v : 0.2f * v;
          float a = __expf(v - mh[h]) / sh[h];
          if (MODE == 1) a = 0.95f * a + 0.05f * aprev[(size_t)e * 4 + h];
          if (MODE == 2) a = 0.95f * a + 0.0125f * (aprev[(size_t)e * 4] + aprev[(size_t)e * 4 + 1]
                                                  + aprev[(size_t)e * 4 + 2] + aprev[(size_t)e * 4 + 3]);
          aout[(size_t)e * H + h] = a;
        }
      }
    }
    for (int b = 0; b < cnt; b++){
      int e = eid[off + b]; int s = srcv[e]; int r = et[e];
      const short* row = featb + (size_t)s * (H * 192);
      float apm[4] = {};
      if (MODE > 0){
#pragma unroll
        for (int q = 0; q < 4; q++) apm[q] = aprev[(size_t)e * 4 + q];
      }
      if (lane < NC){
        float v = el[s * H + h0] + ern[h0] + ee5[r * H + h0];
        v = (v >= 0.f) ? v : 0.2f * v;
        float a = __expf(v - mh[h0]) / sh[h0];
        if (MODE == 1) a = 0.95f * a + 0.05f * apm[h0];
        if (MODE == 2) a = 0.95f * a + 0.0125f * (apm[0] + apm[1] + apm[2] + apm[3]);
        s16x8 vv = *(const s16x8*)(row + c0 * 8);
#pragma unroll
        for (int i = 0; i < 8; i++) acc0[i] += a * bf2f(vv[i]);
      }
      if (H == 4 && lane < 32){
        float v = el[s * H + h1] + ern[h1] + ee5[r * H + h1];
        v = (v >= 0.f) ? v : 0.2f * v;
        float a = __expf(v - mh[h1]) / sh[h1];
        if (MODE == 1) a = 0.95f * a + 0.05f * apm[h1];
        s16x8 vv = *(const s16x8*)(row + c1 * 8);
#pragma unroll
        for (int i = 0; i < 8; i++) acc1[i] += a * bf2f(vv[i]);
      }
    }
  }
  // ---- epilogue (cnt==0 -> zeros) ----
  if (lane < NC){
    int dd = c0 * 8, h = dd / 192, rr = dd % 192, t = rr / 64, j = rr % 64;
    if (ACT){
#pragma unroll
      for (int i = 0; i < 8; i++) acc0[i] = (acc0[i] > 0.f) ? acc0[i] : expm1f(acc0[i]);
    }
    if (outb){
      s16x8 o;
#pragma unroll
      for (int i = 0; i < 8; i++) o[i] = f2bf(acc0[i]);
      *(s16x8*)(outb + ((size_t)(t * NPAD) + n) * 256 + h * 64 + j) = o;
    } else {
#pragma unroll
      for (int i = 0; i < 8; i++) outf[(size_t)n * 192 + dd + i] = acc0[i];
    }
  }
  if (H == 4 && lane < 32){
    int dd = c1 * 8, h = dd / 192, rr = dd % 192, t = rr / 64, j = rr % 64;
    if (ACT){
#pragma unroll
      for (int i = 0; i < 8; i++) acc1[i] = (acc1[i] > 0.f) ? acc1[i] : expm1f(acc1[i]);
    }
    if (outb){
      s16x8 o;
#pragma unroll
      for (int i = 0; i < 8; i++) o[i] = f2bf(acc1[i]);
      *(s16x8*)(outb + ((size_t)(t * NPAD) + n) * 256 + h * 64 + j) = o;
    }
  }
}

// ---------------- DistMult via MFMA ----------------
__global__ void distmult_mfma(const short* __restrict__ o_b, const short* __restrict__ Mt,
                              const int* __restrict__ pairs, const int* __restrict__ left,
                              const int* __restrict__ right, const int* __restrict__ mid,
                              float* __restrict__ score){
  const int pt = blockIdx.x, ct = blockIdx.y;
  const int tid = threadIdx.x;
  const int w = tid >> 6, lane = tid & 63;
  const int quad = lane >> 4, ln = lane & 15;
  __shared__ __attribute__((aligned(16))) short smem[8192];
  short* A_s = smem;
  short* B_s = smem + 2048;
  __shared__ int pid_s[64];
  __shared__ int lbase[64];
  if (tid < 64){
    int p = pairs[pt * 64 + tid];
    pid_s[tid] = p;
    lbase[tid] = (p >= 0) ? left[p] * 768 : 0;
  }
  __syncthreads();
  int p0 = pid_s[0];
  if (p0 < 0) return;
  const int r = mid[p0];
  const short* Mr = Mt + (size_t)r * 768 * 768;
  f32x4 acc[8] = {};
  for (int kk = 0; kk < 768; kk += 32){
    {
      int row = tid >> 2, chunk = tid & 3;
      s16x8 v = *(const s16x8*)(o_b + (size_t)lbase[row] + kk + chunk * 8);
      *(s16x8*)(A_s + row * 32 + chunk * 8) = v;
    }
    {
      int row = tid >> 1, half = tid & 1;
      const s16x8* g = (const s16x8*)(Mr + (size_t)(ct * 128 + row) * 768 + kk + half * 16);
      s16x8 v0 = g[0], v1 = g[1];
      *(s16x8*)(B_s + row * 32 + half * 16) = v0;
      *(s16x8*)(B_s + row * 32 + half * 16 + 8) = v1;
    }
    __syncthreads();
    s16x8 af = *(s16x8*)(A_s + (w * 16 + ln) * 32 + quad * 8);
#pragma unroll
    for (int b = 0; b < 8; b++){
      s16x8 bf = *(s16x8*)(B_s + (b * 16 + ln) * 32 + quad * 8);
      acc[b] = __builtin_amdgcn_mfma_f32_16x16x32_bf16(af, bf, acc[b], 0, 0, 0);
    }
    __syncthreads();
  }
  short* RE_s = smem;
  {
    int row = tid >> 2, quarter = tid & 3;
    int p = pid_s[row];
    s16x8 v0 = {}, v1 = {}, v2 = {}, v3 = {};
    if (p >= 0){
      const s16x8* g = (const s16x8*)(o_b + (size_t)right[p] * 768 + ct * 128 + quarter * 32);
      v0 = g[0]; v1 = g[1]; v2 = g[2]; v3 = g[3];
    }
    __syncthreads();
    short* dst = RE_s + row * 128 + quarter * 32;
    *(s16x8*)(dst)      = v0;
    *(s16x8*)(dst + 8)  = v1;
    *(s16x8*)(dst + 16) = v2;
    *(s16x8*)(dst + 24) = v3;
  }
  __syncthreads();
#pragma unroll
  for (int i = 0; i < 4; i++){
    int row = w * 16 + quad * 4 + i;
    float s = 0.f;
#pragma unroll
    for (int b = 0; b < 8; b++)
      s += acc[b][i] * bf2f(RE_s[row * 128 + b * 16 + ln]);
    s += __shfl_xor(s, 1); s += __shfl_xor(s, 2);
    s += __shfl_xor(s, 4); s += __shfl_xor(s, 8);
    if (ln == 0){
      int p = pid_s[row];
      if (p >= 0) atomicAdd(&score[p], s);
    }
  }
}

__global__ void sigmoid_k(const float* __restrict__ score, float* __restrict__ out){
  int i = blockIdx.x * 256 + threadIdx.x;
  if (i < N_PAIRS) out[i] = 1.f / (1.f + __expf(-score[i]));
}

// ---------------- launcher ----------------
extern "C" void kernel_launch(void* const* d_in, const int* in_sizes, int n_in,
                              void* d_out, int out_size, void* d_ws, size_t ws_size,
                              hipStream_t stream){
  const float* f0 = (const float*)d_in[0];
  const float* w0 = (const float*)d_in[1];
  const float* b0 = (const float*)d_in[2];
  const float* f1 = (const float*)d_in[3];
  const float* w1 = (const float*)d_in[4];
  const float* b1 = (const float*)d_in[5];
  const float* f2 = (const float*)d_in[6];
  const float* w2_ = (const float*)d_in[7];
  const float* b2 = (const float*)d_in[8];
  const float* lW[3]  = {(const float*)d_in[9],  (const float*)d_in[15], (const float*)d_in[21]};
  const float* lal[3] = {(const float*)d_in[10], (const float*)d_in[16], (const float*)d_in[22]};
  const float* lar[3] = {(const float*)d_in[11], (const float*)d_in[17], (const float*)d_in[23]};
  const float* lee[3] = {(const float*)d_in[12], (const float*)d_in[18], (const float*)d_in[24]};
  const float* lwe[3] = {(const float*)d_in[13], (const float*)d_in[19], (const float*)d_in[25]};
  const float* lae[3] = {(const float*)d_in[14], (const float*)d_in[20], (const float*)d_in[26]};
  const float* dmW = (const float*)d_in[27];
  const int* efeat = (const int*)d_in[28];
  const int* srcv  = (const int*)d_in[29];
  const int* dstv  = (const int*)d_in[30];
  const int* left  = (const int*)d_in[31];
  const int* right = (const int*)d_in[32];
  const int* midv  = (const int*)d_in[33];
  float* out = (float*)d_out;

  // ---- workspace layout (~131 MB) ----
  short* feat_b = (short*)d_ws;              // 15,360,000 shorts  bf16 feat [N,H,192]
  float* hbuf  = (float*)(feat_b + 15360000);// 3,840,000   h / layer2-out [N,192]
  float* aA    = hbuf + 3840000;             // 800,000
  float* aB    = aA + 800000;                // 800,000
  float* elf   = aB + 800000;                // 80,000
  float* erf   = elf + 80000;                // 80,000
  float* ee5f  = erf + 80000;                // 32
  float* score = ee5f + 32;                  // 10,016
  int* csr_cnt = (int*)(score + 10016);      // 20,000
  int* csr_off = csr_cnt + 20000;            // 20,004
  int* csr_pos = csr_off + 20004;            // 20,000
  int* eidb    = csr_pos + 20000;            // 200,000
  int* cnt5    = eidb + 200000;              // 8
  int* off5    = cnt5 + 8;                   // 8
  int* pos5    = off5 + 8;                   // 8
  int* pairs   = pos5 + 8;                   // 10,368
  short* o_b   = (short*)(pairs + PAIR_PAD); // 15,360,000  o bf16 [N,768]
  short* Xb0   = o_b + 15360000;             // 3*NPAD*64  = 3,858,432
  short* Xb12  = Xb0 + 3858432;              // 3*NPAD*256 = 15,433,728
  short* Wt0   = Xb12 + 15433728;            // 3*256*64
  short* Wt1   = Wt0 + 49152;                // 3*256*256
  short* Wt2   = Wt1 + 196608;               // 3*64*256
  short* Mt    = Wt2 + 49152;                // 5*768*768

  zero_init<<<80, 256, 0, stream>>>(csr_cnt, cnt5, pos5, score, pairs, Xb0, Xb12);
  build_h<<<N_NODES, 64, 0, stream>>>(f0, w0, b0, f1, w1, b1, f2, w2_, b2, hbuf, Xb0);
  emb_f32<<<5000, 256, 0, stream>>>(hbuf, o_b, 0);
  count_k<<<782, 256, 0, stream>>>(dstv, csr_cnt, midv, cnt5);
  scan_k<<<1, 256, 0, stream>>>(csr_cnt, csr_off, csr_pos, cnt5, off5);
  scatter_k<<<782, 256, 0, stream>>>(dstv, csr_pos, eidb, midv, off5, pos5, pairs);

  // weight prep (bf16 transposes)
  { dim3 g(2, 8, 3);   transpose_bf16<<<g, 256, 0, stream>>>(lW[0], Wt0, 64, 256); }
  { dim3 g(8, 8, 3);   transpose_bf16<<<g, 256, 0, stream>>>(lW[1], Wt1, 256, 256); }
  { dim3 g(8, 2, 3);   transpose_bf16<<<g, 256, 0, stream>>>(lW[2], Wt2, 256, 64); }
  { dim3 g(24, 24, 5); transpose_bf16<<<g, 256, 0, stream>>>(dmW, Mt, 768, 768); }

  // layer 0 (H=4, no residual, ELU)
  ee5_kernel<<<5, 256, 0, stream>>>(lee[0], lwe[0], lae[0], ee5f, 4);
  { dim3 g(NPAD / 128, 4, 3); mfma_proj<64, 256><<<g, 256, 0, stream>>>(Xb0, Wt0, feat_b); }
  elr_kernel<<<20000, 256, 0, stream>>>(feat_b, lal[0], lar[0], elf, erf, 4, 80000);
  gat_fused<4, 0, 1><<<5000, 256, 0, stream>>>(csr_off, eidb, srcv, efeat, elf, erf, ee5f,
                                               nullptr, aA, feat_b, Xb12, nullptr);
  emb_bf16<<<5000, 256, 0, stream>>>(Xb12, o_b, 1);

  // layer 1 (H=4, residual aA, ELU)
  ee5_kernel<<<5, 256, 0, stream>>>(lee[1], lwe[1], lae[1], ee5f, 4);
  { dim3 g(NPAD / 128, 4, 3); mfma_proj<256, 256><<<g, 256, 0, stream>>>(Xb12, Wt1, feat_b); }
  elr_kernel<<<20000, 256, 0, stream>>>(feat_b, lal[1], lar[1], elf, erf, 4, 80000);
  gat_fused<4, 1, 1><<<5000, 256, 0, stream>>>(csr_off, eidb, srcv, efeat, elf, erf, ee5f,
                                               aA, aB, feat_b, Xb12, nullptr);
  emb_bf16<<<5000, 256, 0, stream>>>(Xb12, o_b, 2);

  // layer 2 (H=1, blend vs mean of a1, no activation)
  ee5_kernel<<<5, 64, 0, stream>>>(lee[2], lwe[2], lae[2], ee5f, 1);
  { dim3 g(NPAD / 128, 1, 3); mfma_proj<256, 64><<<g, 256, 0, stream>>>(Xb12, Wt2, feat_b); }
  elr_kernel<<<5000, 256, 0, stream>>>(feat_b, lal[2], lar[2], elf, erf, 1, 20000);
  gat_fused<1, 2, 0><<<5000, 256, 0, stream>>>(csr_off, eidb, srcv, efeat, elf, erf, ee5f,
                                               aB, nullptr, feat_b, nullptr, hbuf);
  emb_f32<<<5000, 256, 0, stream>>>(hbuf, o_b, 3);

  // DistMult + sigmoid
  { dim3 g(DM_TILES, 6); distmult_mfma<<<g, 256, 0, stream>>>(o_b, Mt, pairs, left, right, midv, score); }
  sigmoid_k<<<40, 256, 0, stream>>>(score, out);
}

// Round 5
// 573.050 us; speedup vs baseline: 3.3087x; 1.2188x over previous
//
#include <hip/hip_runtime.h>
#include <math.h>

// ---------------- constants ----------------
#define N_NODES 20000
#define NPAD    20096          // 157*128
#define N_EDGES 200000
#define N_PAIRS 10000
#define PAIR_PAD 10368         // 162*64
#define DM_TILES 162

typedef __attribute__((ext_vector_type(8))) short s16x8;
typedef __attribute__((ext_vector_type(4))) float f32x4;

__device__ inline float wave_max(float v){
  for (int o = 32; o > 0; o >>= 1) v = fmaxf(v, __shfl_xor(v, o));
  return v;
}
__device__ inline float wave_sum(float v){
  for (int o = 32; o > 0; o >>= 1) v += __shfl_xor(v, o);
  return v;
}
__device__ inline short f2bf(float x){
  union { float f; unsigned u; } v; v.f = x;
  unsigned r = (v.u + 0x7FFFu + ((v.u >> 16) & 1u)) >> 16;
  return (short)r;
}
__device__ inline float bf2f(short s){
  union { unsigned u; float f; } v; v.u = ((unsigned)(unsigned short)s) << 16;
  return v.f;
}

// ---------------- input linears -> Xb0 bf16 [3][NPAD][64] + o_b slice 0 ----------------
__global__ void build_h(const float* __restrict__ f0, const float* __restrict__ w0, const float* __restrict__ b0,
                        const float* __restrict__ f1, const float* __restrict__ w1, const float* __restrict__ b1,
                        const float* __restrict__ f2, const float* __restrict__ w2, const float* __restrict__ b2,
                        short* __restrict__ Xb0, short* __restrict__ o_b){
  int n = blockIdx.x, lane = threadIdx.x;
  int t, idx, C; const float *f, *w, *b;
  if (n < 8000)       { t = 0; idx = n;         C = 256; f = f0; w = w0; b = b0; }
  else if (n < 14000) { t = 1; idx = n - 8000;  C = 128; f = f1; w = w1; b = b1; }
  else                { t = 2; idx = n - 14000; C = 64;  f = f2; w = w2; b = b2; }
  __shared__ float xs[256];
  for (int c = lane; c < C; c += 64) xs[c] = f[(size_t)idx * C + c];
  __syncthreads();
  float acc = b[lane];
  for (int c = 0; c < C; c++) acc += xs[c] * w[c * 64 + lane];
  for (int tt = 0; tt < 3; tt++)
    Xb0[((size_t)(tt * NPAD) + n) * 64 + lane] = f2bf((tt == t) ? acc : 0.f);
  // emb slice 0: l2BySlot of h (only slot t nonzero)
  float ss = wave_sum(acc * acc);
  float sc = 1.f / fmaxf(sqrtf(ss), 1e-12f);
  for (int tt = 0; tt < 3; tt++)
    o_b[(size_t)n * 768 + tt * 256 + lane] = f2bf((tt == t) ? acc * sc : 0.f);
}

// ---------------- init ----------------
__global__ void zero_init(int* __restrict__ csr_cnt, int* __restrict__ cnt5, int* __restrict__ pos5,
                          float* __restrict__ score, int* __restrict__ pairs,
                          short* __restrict__ Xb0, short* __restrict__ Xb12){
  int i = blockIdx.x * 256 + threadIdx.x;   // 80*256 = 20480
  if (i < N_NODES) csr_cnt[i] = 0;
  if (i < 5) { cnt5[i * 16] = 0; pos5[i * 16] = 0; }
  if (i < N_PAIRS) score[i] = 0.f;
  if (i < PAIR_PAD) pairs[i] = -1;
  s16x8 z = {};
  if (i < 4608){  // Xb12 pad rows: 3 * 96 * 256 shorts
    int t = (i * 16) / 24576, off = (i * 16) % 24576;
    short* p = Xb12 + ((size_t)(t * NPAD + N_NODES)) * 256 + off;
    *(s16x8*)p = z; *(s16x8*)(p + 8) = z;
  }
  if (i < 1152){  // Xb0 pad rows: 3 * 96 * 64 shorts
    int t = (i * 16) / 6144, off = (i * 16) % 6144;
    short* p = Xb0 + ((size_t)(t * NPAD + N_NODES)) * 64 + off;
    *(s16x8*)p = z; *(s16x8*)(p + 8) = z;
  }
}

__global__ void count_k(const int* __restrict__ dst, int* __restrict__ csr_cnt,
                        const int* __restrict__ mid, int* __restrict__ cnt5){
  int e = blockIdx.x * 256 + threadIdx.x;
  int lane = threadIdx.x & 63;
  if (e < N_EDGES) atomicAdd(&csr_cnt[dst[e]], 1);
  int r_mine = (e < N_PAIRS) ? mid[e] : -1;
#pragma unroll
  for (int r = 0; r < 5; r++){
    unsigned long long mask = __ballot(r_mine == r);
    if (mask){
      int leader = __ffsll((long long)mask) - 1;
      if (lane == leader) atomicAdd(&cnt5[r * 16], __popcll(mask));
    }
  }
}

__global__ void scan_k(const int* __restrict__ cnt, int* __restrict__ coff, int* __restrict__ cpos,
                       const int* __restrict__ cnt5, int* __restrict__ off5){
  __shared__ int sums[256];
  int t = threadIdx.x;
  const int CH = 79;
  int base = t * CH;
  int s = 0;
  for (int i = 0; i < CH; i++){ int idx = base + i; if (idx < N_NODES) s += cnt[idx]; }
  sums[t] = s;
  __syncthreads();
  for (int o = 1; o < 256; o <<= 1){
    int v = (t >= o) ? sums[t - o] : 0;
    __syncthreads();
    sums[t] += v;
    __syncthreads();
  }
  int run = sums[t] - s;
  for (int i = 0; i < CH; i++){
    int idx = base + i;
    if (idx < N_NODES){ coff[idx] = run; cpos[idx * 16] = run; run += cnt[idx]; }
  }
  if (t == 255) coff[N_NODES] = N_EDGES;
  if (t == 0){
    int r0 = 0;
    for (int r = 0; r < 5; r++){ off5[r] = r0; r0 += ((cnt5[r * 16] + 63) >> 6) << 6; }
  }
}

__global__ void scatter_k(const int* __restrict__ dst, int* __restrict__ cpos, int* __restrict__ eid,
                          const int* __restrict__ mid, const int* __restrict__ off5,
                          int* __restrict__ pos5, int* __restrict__ pairs){
  int e = blockIdx.x * 256 + threadIdx.x;
  int lane = threadIdx.x & 63;
  if (e < N_EDGES){
    int p = atomicAdd(&cpos[dst[e] * 16], 1);
    eid[p] = e;
  }
  // pairs: wave-aggregated binning (1 returning atomic per wave per relation)
  int r_mine = (e < N_PAIRS) ? mid[e] : -1;
#pragma unroll
  for (int r = 0; r < 5; r++){
    unsigned long long mask = __ballot(r_mine == r);
    if (mask){
      int cnt = __popcll(mask);
      int leader = __ffsll((long long)mask) - 1;
      int base = 0;
      if (lane == leader) base = atomicAdd(&pos5[r * 16], cnt);
      base = __shfl(base, leader);
      if (r_mine == r){
        int rank = __popcll(mask & ((1ull << lane) - 1ull));
        pairs[off5[r] + base + rank] = e;
      }
    }
  }
}

// ---------------- ee5 tables for all 3 layers ----------------
__global__ void ee5_all(const float* __restrict__ ee0, const float* __restrict__ we0, const float* __restrict__ ae0,
                        const float* __restrict__ ee1, const float* __restrict__ we1, const float* __restrict__ ae1,
                        const float* __restrict__ ee2, const float* __restrict__ we2, const float* __restrict__ ae2,
                        float* __restrict__ ee5f){
  int r = blockIdx.x, L = blockIdx.y;
  int H = (L == 2) ? 1 : 4;
  const float* eetab = (L == 0) ? ee0 : ((L == 1) ? ee1 : ee2);
  const float* We    = (L == 0) ? we0 : ((L == 1) ? we1 : we2);
  const float* ae    = (L == 0) ? ae0 : ((L == 1) ? ae1 : ae2);
  int h = threadIdx.x >> 6, lane = threadIdx.x & 63;
  if (h >= H) return;
  float v = 0.f;
  for (int k = 0; k < 64; k++) v += eetab[r * 64 + k] * We[k * H * 64 + h * 64 + lane];
  v *= ae[h * 64 + lane];
  v = wave_sum(v);
  if (lane == 0) ee5f[L * 32 + r * H + h] = v;
}

// ---------------- fp32 [R][Cc] -> bf16 [Cc][R] (batched transpose) ----------------
__global__ void transpose_bf16(const float* __restrict__ src, short* __restrict__ dst, int R, int Cc){
  __shared__ float tile[32][33];
  const float* s = src + (size_t)blockIdx.z * R * Cc;
  short* d = dst + (size_t)blockIdx.z * R * Cc;
  int r0 = blockIdx.x * 32, c0 = blockIdx.y * 32;
  int tx = threadIdx.x & 31, ty = threadIdx.x >> 5;   // 8 rows of 32
  for (int i = 0; i < 32; i += 8){
    int r = r0 + ty + i;
    tile[ty + i][tx] = (r < R && c0 + tx < Cc) ? s[(size_t)r * Cc + c0 + tx] : 0.f;
  }
  __syncthreads();
  for (int i = 0; i < 32; i += 8){
    int c = c0 + ty + i;
    if (c < Cc && r0 + tx < R)
      d[(size_t)c * R + r0 + tx] = f2bf(tile[tx][ty + i]);
  }
}

// ---------------- MFMA slot projection -> bf16 feat ----------------
template<int C, int NO>
__global__ void mfma_proj(const short* __restrict__ Xb, const short* __restrict__ Wt,
                          short* __restrict__ featb){
  constexpr int H = NO / 64;
  const int n0 = blockIdx.x * 128;
  const int ct = blockIdx.y;
  const int t  = blockIdx.z;
  const int tid = threadIdx.x;
  const int w = tid >> 6, lane = tid & 63;
  const int quad = lane >> 4, ln = lane & 15;
  __shared__ __attribute__((aligned(16))) short A_s[128 * 32];
  __shared__ __attribute__((aligned(16))) short B_s[64 * 32];
  const short* Xt  = Xb + (size_t)t * NPAD * C;
  const short* Wtt = Wt + ((size_t)t * NO + ct * 64) * C;
  f32x4 acc[2][4] = {};
  for (int kk = 0; kk < C; kk += 32){
    {
      int row = tid >> 1, half = tid & 1;
      const s16x8* g = (const s16x8*)(Xt + (size_t)(n0 + row) * C + kk + half * 16);
      s16x8 v0 = g[0], v1 = g[1];
      *(s16x8*)(A_s + row * 32 + half * 16) = v0;
      *(s16x8*)(A_s + row * 32 + half * 16 + 8) = v1;
    }
    {
      int row = tid >> 2, chunk = tid & 3;
      s16x8 v = *(const s16x8*)(Wtt + (size_t)row * C + kk + chunk * 8);
      *(s16x8*)(B_s + row * 32 + chunk * 8) = v;
    }
    __syncthreads();
    s16x8 af0 = *(s16x8*)(A_s + (w * 32 + ln) * 32 + quad * 8);
    s16x8 af1 = *(s16x8*)(A_s + (w * 32 + 16 + ln) * 32 + quad * 8);
    s16x8 bf[4];
#pragma unroll
    for (int b = 0; b < 4; b++) bf[b] = *(s16x8*)(B_s + (b * 16 + ln) * 32 + quad * 8);
#pragma unroll
    for (int b = 0; b < 4; b++){
      acc[0][b] = __builtin_amdgcn_mfma_f32_16x16x32_bf16(af0, bf[b], acc[0][b], 0, 0, 0);
      acc[1][b] = __builtin_amdgcn_mfma_f32_16x16x32_bf16(af1, bf[b], acc[1][b], 0, 0, 0);
    }
    __syncthreads();
  }
#pragma unroll
  for (int ar = 0; ar < 2; ar++){
#pragma unroll
    for (int i = 0; i < 4; i++){
      int n = n0 + w * 32 + ar * 16 + quad * 4 + i;
      if (n >= N_NODES) continue;
#pragma unroll
      for (int b = 0; b < 4; b++){
        int d = ct * 64 + b * 16 + ln;
        int h = d >> 6, jj = d & 63;
        featb[((size_t)n * H + h) * 192 + t * 64 + jj] = f2bf(acc[ar][b][i]);
      }
    }
  }
}

// ---------------- el/er from bf16 feat ----------------
__global__ void elr_kernel(const short* __restrict__ featb, const float* __restrict__ al,
                           const float* __restrict__ ar, float* __restrict__ el,
                           float* __restrict__ er, int H, int total){
  int wid = threadIdx.x >> 6, lane = threadIdx.x & 63;
  int gw = blockIdx.x * 4 + wid;
  if (gw >= total) return;
  int h = gw % H;
  const short* f = featb + (size_t)gw * 192;
  float sl = 0.f, sr = 0.f;
  for (int i = 0; i < 3; i++){
    int dd = i * 64 + lane;
    float v = bf2f(f[dd]);
    sl += v * al[h * 192 + dd];
    sr += v * ar[h * 192 + dd];
  }
  sl = wave_sum(sl); sr = wave_sum(sr);
  if (lane == 0){ el[gw] = sl; er[gw] = sr; }
}

// ---------------- fused edge-softmax + aggregation + emb (wave per node) ----------------
// MODE 0: a=softmax -> aout[e*4+h]; MODE 1: a=.95sm+.05*aprev[e,h] -> aout
// MODE 2 (H=1): a=.95sm+.05*mean(aprev[e,:]); no aout
// ACT: ELU. outb: bf16 [3][NPAD][H*64] (next layer X, H=4 only)
// o_b slice kslice written from fp32 out (head-mean + l2BySlot)
template<int H, int MODE, int ACT>
__global__ __launch_bounds__(256) void gat_fused(
    const int* __restrict__ csr_off, const int* __restrict__ eid,
    const int* __restrict__ srcv, const int* __restrict__ et,
    const float* __restrict__ el, const float* __restrict__ er, const float* __restrict__ ee5,
    const float* __restrict__ aprev, float* __restrict__ aout,
    const short* __restrict__ featb, short* __restrict__ outb,
    short* __restrict__ o_b, int kslice){
  const int wid = threadIdx.x >> 6, lane = threadIdx.x & 63;
  const int n = blockIdx.x * 4 + wid;
  if (n >= N_NODES) return;
  const int off = csr_off[n];
  const int cnt = csr_off[n + 1] - off;
  __shared__ float a_s[4][64][4];
  __shared__ int src_s[4][64];
  __shared__ float out_s[4][H * 192];
  constexpr int NC = H * 192 / 8;            // 96 (H=4) or 24 (H=1)
  const int c0 = lane;
  const int h0 = (c0 / 24) % H;
  const int c1 = lane + 64;                  // H=4, lane<32 only
  const int h1 = (c1 / 24) % H;
  float acc0[8] = {}, acc1[8] = {};
  float ern[H];
#pragma unroll
  for (int h = 0; h < H; h++) ern[h] = er[n * H + h];

  if (cnt > 0 && cnt <= 64){
    // ---- phase 1: lane = edge ----
    int e = -1, sidx = 0;
    if (lane < cnt){ e = eid[off + lane]; sidx = srcv[e]; src_s[wid][lane] = sidx; }
    float lg[H];
#pragma unroll
    for (int h = 0; h < H; h++) lg[h] = -1e30f;
    if (lane < cnt){
      int r = et[e];
#pragma unroll
      for (int h = 0; h < H; h++){
        float v = el[sidx * H + h] + ern[h] + ee5[r * H + h];
        lg[h] = (v >= 0.f) ? v : 0.2f * v;
      }
    }
    float ap[4] = {};
    if (MODE > 0 && lane < cnt){
#pragma unroll
      for (int q = 0; q < 4; q++) ap[q] = aprev[(size_t)e * 4 + q];
    }
    float av[H];
#pragma unroll
    for (int h = 0; h < H; h++){
      float mh = wave_max(lg[h]);
      float ex = (lane < cnt) ? __expf(lg[h] - mh) : 0.f;
      float sh = wave_sum(ex);
      float a = ex / sh;
      if (MODE == 1) a = 0.95f * a + 0.05f * ap[h];
      if (MODE == 2) a = 0.95f * a + 0.0125f * (ap[0] + ap[1] + ap[2] + ap[3]);
      av[h] = a;
      if (lane < cnt) a_s[wid][lane][h] = a;
    }
    if (aout && lane < cnt){
#pragma unroll
      for (int h = 0; h < H; h++) aout[(size_t)e * H + h] = av[h];
    }
    // ---- phase 2: lane = chunk ----
    for (int b = 0; b < cnt; b++){
      int s = src_s[wid][b];
      const short* row = featb + (size_t)s * (H * 192);
      if (lane < NC){
        float a = a_s[wid][b][h0];
        s16x8 v = *(const s16x8*)(row + c0 * 8);
#pragma unroll
        for (int i = 0; i < 8; i++) acc0[i] += a * bf2f(v[i]);
      }
      if (H == 4 && lane < 32){
        float a = a_s[wid][b][h1];
        s16x8 v = *(const s16x8*)(row + c1 * 8);
#pragma unroll
        for (int i = 0; i < 8; i++) acc1[i] += a * bf2f(v[i]);
      }
    }
  } else if (cnt > 64){
    // ---- slow path (recompute-based; essentially never taken) ----
    float mh[H], sh[H];
#pragma unroll
    for (int h = 0; h < H; h++){ mh[h] = -1e30f; sh[h] = 0.f; }
    for (int b = lane; b < cnt; b += 64){
      int e = eid[off + b]; int s = srcv[e]; int r = et[e];
#pragma unroll
      for (int h = 0; h < H; h++){
        float v = el[s * H + h] + ern[h] + ee5[r * H + h];
        v = (v >= 0.f) ? v : 0.2f * v;
        mh[h] = fmaxf(mh[h], v);
      }
    }
#pragma unroll
    for (int h = 0; h < H; h++) mh[h] = wave_max(mh[h]);
    for (int b = lane; b < cnt; b += 64){
      int e = eid[off + b]; int s = srcv[e]; int r = et[e];
#pragma unroll
      for (int h = 0; h < H; h++){
        float v = el[s * H + h] + ern[h] + ee5[r * H + h];
        v = (v >= 0.f) ? v : 0.2f * v;
        sh[h] += __expf(v - mh[h]);
      }
    }
#pragma unroll
    for (int h = 0; h < H; h++) sh[h] = wave_sum(sh[h]);
    if (aout){
      for (int b = lane; b < cnt; b += 64){
        int e = eid[off + b]; int s = srcv[e]; int r = et[e];
#pragma unroll
        for (int h = 0; h < H; h++){
          float v = el[s * H + h] + ern[h] + ee5[r * H + h];
          v = (v >= 0.f) ? v : 0.2f * v;
          float a = __expf(v - mh[h]) / sh[h];
          if (MODE == 1) a = 0.95f * a + 0.05f * aprev[(size_t)e * 4 + h];
          if (MODE == 2) a = 0.95f * a + 0.0125f * (aprev[(size_t)e * 4] + aprev[(size_t)e * 4 + 1]
                                                  + aprev[(size_t)e * 4 + 2] + aprev[(size_t)e * 4 + 3]);
          aout[(size_t)e * H + h] = a;
        }
      }
    }
    for (int b = 0; b < cnt; b++){
      int e = eid[off + b]; int s = srcv[e]; int r = et[e];
      const short* row = featb + (size_t)s * (H * 192);
      float apm[4] = {};
      if (MODE > 0){
#pragma unroll
        for (int q = 0; q < 4; q++) apm[q] = aprev[(size_t)e * 4 + q];
      }
      if (lane < NC){
        float v = el[s * H + h0] + ern[h0] + ee5[r * H + h0];
        v = (v >= 0.f) ? v : 0.2f * v;
        float a = __expf(v - mh[h0]) / sh[h0];
        if (MODE == 1) a = 0.95f * a + 0.05f * apm[h0];
        if (MODE == 2) a = 0.95f * a + 0.0125f * (apm[0] + apm[1] + apm[2] + apm[3]);
        s16x8 vv = *(const s16x8*)(row + c0 * 8);
#pragma unroll
        for (int i = 0; i < 8; i++) acc0[i] += a * bf2f(vv[i]);
      }
      if (H == 4 && lane < 32){
        float v = el[s * H + h1] + ern[h1] + ee5[r * H + h1];
        v = (v >= 0.f) ? v : 0.2f * v;
        float a = __expf(v - mh[h1]) / sh[h1];
        if (MODE == 1) a = 0.95f * a + 0.05f * apm[h1];
        s16x8 vv = *(const s16x8*)(row + c1 * 8);
#pragma unroll
        for (int i = 0; i < 8; i++) acc1[i] += a * bf2f(vv[i]);
      }
    }
  }
  // ---- epilogue (cnt==0 -> zeros): ELU, write next-layer X, stage LDS for emb ----
  if (lane < NC){
    int dd = c0 * 8, h = dd / 192, rr = dd % 192, t = rr / 64, j = rr % 64;
    if (ACT){
#pragma unroll
      for (int i = 0; i < 8; i++) acc0[i] = (acc0[i] > 0.f) ? acc0[i] : expm1f(acc0[i]);
    }
#pragma unroll
    for (int i = 0; i < 8; i++) out_s[wid][dd + i] = acc0[i];
    if (outb){
      s16x8 o;
#pragma unroll
      for (int i = 0; i < 8; i++) o[i] = f2bf(acc0[i]);
      *(s16x8*)(outb + ((size_t)(t * NPAD) + n) * 256 + h * 64 + j) = o;
    }
  }
  if (H == 4 && lane < 32){
    int dd = c1 * 8, h = dd / 192, rr = dd % 192, t = rr / 64, j = rr % 64;
    if (ACT){
#pragma unroll
      for (int i = 0; i < 8; i++) acc1[i] = (acc1[i] > 0.f) ? acc1[i] : expm1f(acc1[i]);
    }
#pragma unroll
    for (int i = 0; i < 8; i++) out_s[wid][dd + i] = acc1[i];
    if (outb){
      s16x8 o;
#pragma unroll
      for (int i = 0; i < 8; i++) o[i] = f2bf(acc1[i]);
      *(s16x8*)(outb + ((size_t)(t * NPAD) + n) * 256 + h * 64 + j) = o;
    }
  }
  // intra-wave LDS RAW: safe (program order within a wave; compiler inserts lgkmcnt)
  for (int t = 0; t < 3; t++){
    float v;
    if (H == 4)
      v = 0.25f * (out_s[wid][t * 64 + lane] + out_s[wid][192 + t * 64 + lane] +
                   out_s[wid][384 + t * 64 + lane] + out_s[wid][576 + t * 64 + lane]);
    else
      v = out_s[wid][t * 64 + lane];
    float ss = wave_sum(v * v);
    float sc = 1.f / fmaxf(sqrtf(ss), 1e-12f);
    o_b[(size_t)n * 768 + t * 256 + kslice * 64 + lane] = f2bf(v * sc);
  }
}

// ---------------- DistMult via MFMA ----------------
__global__ void distmult_mfma(const short* __restrict__ o_b, const short* __restrict__ Mt,
                              const int* __restrict__ pairs, const int* __restrict__ left,
                              const int* __restrict__ right, const int* __restrict__ mid,
                              float* __restrict__ score){
  const int pt = blockIdx.x, ct = blockIdx.y;
  const int tid = threadIdx.x;
  const int w = tid >> 6, lane = tid & 63;
  const int quad = lane >> 4, ln = lane & 15;
  __shared__ __attribute__((aligned(16))) short smem[8192];
  short* A_s = smem;
  short* B_s = smem + 2048;
  __shared__ int pid_s[64];
  __shared__ int lbase[64];
  if (tid < 64){
    int p = pairs[pt * 64 + tid];
    pid_s[tid] = p;
    lbase[tid] = (p >= 0) ? left[p] * 768 : 0;
  }
  __syncthreads();
  int p0 = pid_s[0];
  if (p0 < 0) return;
  const int r = mid[p0];
  const short* Mr = Mt + (size_t)r * 768 * 768;
  f32x4 acc[8] = {};
  for (int kk = 0; kk < 768; kk += 32){
    {
      int row = tid >> 2, chunk = tid & 3;
      s16x8 v = *(const s16x8*)(o_b + (size_t)lbase[row] + kk + chunk * 8);
      *(s16x8*)(A_s + row * 32 + chunk * 8) = v;
    }
    {
      int row = tid >> 1, half = tid & 1;
      const s16x8* g = (const s16x8*)(Mr + (size_t)(ct * 128 + row) * 768 + kk + half * 16);
      s16x8 v0 = g[0], v1 = g[1];
      *(s16x8*)(B_s + row * 32 + half * 16) = v0;
      *(s16x8*)(B_s + row * 32 + half * 16 + 8) = v1;
    }
    __syncthreads();
    s16x8 af = *(s16x8*)(A_s + (w * 16 + ln) * 32 + quad * 8);
#pragma unroll
    for (int b = 0; b < 8; b++){
      s16x8 bf = *(s16x8*)(B_s + (b * 16 + ln) * 32 + quad * 8);
      acc[b] = __builtin_amdgcn_mfma_f32_16x16x32_bf16(af, bf, acc[b], 0, 0, 0);
    }
    __syncthreads();
  }
  short* RE_s = smem;
  {
    int row = tid >> 2, quarter = tid & 3;
    int p = pid_s[row];
    s16x8 v0 = {}, v1 = {}, v2 = {}, v3 = {};
    if (p >= 0){
      const s16x8* g = (const s16x8*)(o_b + (size_t)right[p] * 768 + ct * 128 + quarter * 32);
      v0 = g[0]; v1 = g[1]; v2 = g[2]; v3 = g[3];
    }
    __syncthreads();
    short* dst = RE_s + row * 128 + quarter * 32;
    *(s16x8*)(dst)      = v0;
    *(s16x8*)(dst + 8)  = v1;
    *(s16x8*)(dst + 16) = v2;
    *(s16x8*)(dst + 24) = v3;
  }
  __syncthreads();
#pragma unroll
  for (int i = 0; i < 4; i++){
    int row = w * 16 + quad * 4 + i;
    float s = 0.f;
#pragma unroll
    for (int b = 0; b < 8; b++)
      s += acc[b][i] * bf2f(RE_s[row * 128 + b * 16 + ln]);
    s += __shfl_xor(s, 1); s += __shfl_xor(s, 2);
    s += __shfl_xor(s, 4); s += __shfl_xor(s, 8);
    if (ln == 0){
      int p = pid_s[row];
      if (p >= 0) atomicAdd(&score[p], s);
    }
  }
}

__global__ void sigmoid_k(const float* __restrict__ score, float* __restrict__ out){
  int i = blockIdx.x * 256 + threadIdx.x;
  if (i < N_PAIRS) out[i] = 1.f / (1.f + __expf(-score[i]));
}

// ---------------- launcher ----------------
extern "C" void kernel_launch(void* const* d_in, const int* in_sizes, int n_in,
                              void* d_out, int out_size, void* d_ws, size_t ws_size,
                              hipStream_t stream){
  const float* f0 = (const float*)d_in[0];
  const float* w0 = (const float*)d_in[1];
  const float* b0 = (const float*)d_in[2];
  const float* f1 = (const float*)d_in[3];
  const float* w1 = (const float*)d_in[4];
  const float* b1 = (const float*)d_in[5];
  const float* f2 = (const float*)d_in[6];
  const float* w2_ = (const float*)d_in[7];
  const float* b2 = (const float*)d_in[8];
  const float* lW[3]  = {(const float*)d_in[9],  (const float*)d_in[15], (const float*)d_in[21]};
  const float* lal[3] = {(const float*)d_in[10], (const float*)d_in[16], (const float*)d_in[22]};
  const float* lar[3] = {(const float*)d_in[11], (const float*)d_in[17], (const float*)d_in[23]};
  const float* lee[3] = {(const float*)d_in[12], (const float*)d_in[18], (const float*)d_in[24]};
  const float* lwe[3] = {(const float*)d_in[13], (const float*)d_in[19], (const float*)d_in[25]};
  const float* lae[3] = {(const float*)d_in[14], (const float*)d_in[20], (const float*)d_in[26]};
  const float* dmW = (const float*)d_in[27];
  const int* efeat = (const int*)d_in[28];
  const int* srcv  = (const int*)d_in[29];
  const int* dstv  = (const int*)d_in[30];
  const int* left  = (const int*)d_in[31];
  const int* right = (const int*)d_in[32];
  const int* midv  = (const int*)d_in[33];
  float* out = (float*)d_out;

  // ---- workspace layout ----
  short* feat_b = (short*)d_ws;              // 15,360,000 shorts  bf16 feat [N,H,192]
  float* aA    = (float*)(feat_b + 15360000);// 800,000
  float* aB    = aA + 800000;                // 800,000
  float* elf   = aB + 800000;                // 80,000
  float* erf   = elf + 80000;                // 80,000
  float* ee5f  = erf + 80000;                // 96 (3 layers x 32)
  float* score = ee5f + 96;                  // 10,016
  int* csr_cnt = (int*)(score + 10016);      // 20,000
  int* csr_off = csr_cnt + 20000;            // 20,004
  int* csr_pos = csr_off + 20004;            // 320,000 (padded x16)
  int* eidb    = csr_pos + 320000;           // 200,000
  int* cnt5    = eidb + 200000;              // 80 (padded x16)
  int* off5    = cnt5 + 80;                  // 8
  int* pos5    = off5 + 8;                   // 80 (padded x16)
  int* pairs   = pos5 + 80;                  // 10,368
  short* o_b   = (short*)(pairs + PAIR_PAD); // 15,360,000  o bf16 [N,768]
  short* Xb0   = o_b + 15360000;             // 3*NPAD*64  = 3,858,432
  short* Xb12  = Xb0 + 3858432;              // 3*NPAD*256 = 15,433,728
  short* Wt0   = Xb12 + 15433728;            // 3*256*64
  short* Wt1   = Wt0 + 49152;                // 3*256*256
  short* Wt2   = Wt1 + 196608;               // 3*64*256
  short* Mt    = Wt2 + 49152;                // 5*768*768

  zero_init<<<80, 256, 0, stream>>>(csr_cnt, cnt5, pos5, score, pairs, Xb0, Xb12);
  build_h<<<N_NODES, 64, 0, stream>>>(f0, w0, b0, f1, w1, b1, f2, w2_, b2, Xb0, o_b);
  count_k<<<782, 256, 0, stream>>>(dstv, csr_cnt, midv, cnt5);
  scan_k<<<1, 256, 0, stream>>>(csr_cnt, csr_off, csr_pos, cnt5, off5);
  scatter_k<<<782, 256, 0, stream>>>(dstv, csr_pos, eidb, midv, off5, pos5, pairs);
  { dim3 g(5, 3); ee5_all<<<g, 256, 0, stream>>>(lee[0], lwe[0], lae[0], lee[1], lwe[1], lae[1],
                                                 lee[2], lwe[2], lae[2], ee5f); }

  // weight prep (bf16 transposes)
  { dim3 g(2, 8, 3);   transpose_bf16<<<g, 256, 0, stream>>>(lW[0], Wt0, 64, 256); }
  { dim3 g(8, 8, 3);   transpose_bf16<<<g, 256, 0, stream>>>(lW[1], Wt1, 256, 256); }
  { dim3 g(8, 2, 3);   transpose_bf16<<<g, 256, 0, stream>>>(lW[2], Wt2, 256, 64); }
  { dim3 g(24, 24, 5); transpose_bf16<<<g, 256, 0, stream>>>(dmW, Mt, 768, 768); }

  // layer 0 (H=4, no residual, ELU) -> emb slice 1
  { dim3 g(NPAD / 128, 4, 3); mfma_proj<64, 256><<<g, 256, 0, stream>>>(Xb0, Wt0, feat_b); }
  elr_kernel<<<20000, 256, 0, stream>>>(feat_b, lal[0], lar[0], elf, erf, 4, 80000);
  gat_fused<4, 0, 1><<<5000, 256, 0, stream>>>(csr_off, eidb, srcv, efeat, elf, erf, ee5f,
                                               nullptr, aA, feat_b, Xb12, o_b, 1);

  // layer 1 (H=4, residual aA, ELU) -> emb slice 2
  { dim3 g(NPAD / 128, 4, 3); mfma_proj<256, 256><<<g, 256, 0, stream>>>(Xb12, Wt1, feat_b); }
  elr_kernel<<<20000, 256, 0, stream>>>(feat_b, lal[1], lar[1], elf, erf, 4, 80000);
  gat_fused<4, 1, 1><<<5000, 256, 0, stream>>>(csr_off, eidb, srcv, efeat, elf, erf, ee5f + 32,
                                               aA, aB, feat_b, Xb12, o_b, 2);

  // layer 2 (H=1, blend vs mean of a1, no activation) -> emb slice 3
  { dim3 g(NPAD / 128, 1, 3); mfma_proj<256, 64><<<g, 256, 0, stream>>>(Xb12, Wt2, feat_b); }
  elr_kernel<<<5000, 256, 0, stream>>>(feat_b, lal[2], lar[2], elf, erf, 1, 20000);
  gat_fused<1, 2, 0><<<5000, 256, 0, stream>>>(csr_off, eidb, srcv, efeat, elf, erf, ee5f + 64,
                                               aB, nullptr, feat_b, nullptr, o_b, 3);

  // DistMult + sigmoid
  { dim3 g(DM_TILES, 6); distmult_mfma<<<g, 256, 0, stream>>>(o_b, Mt, pairs, left, right, midv, score); }
  sigmoid_k<<<40, 256, 0, stream>>>(score, out);
}